// Round 5
// baseline (337.950 us; speedup 1.0000x reference)
//
#include <hip/hip_runtime.h>

constexpr int kN  = 16384;
constexpr int kEB = 524288;
constexpr int kET = 262144;
constexpr int kTA = 107;
constexpr float kEps = 1e-5f;
#define HN 256

typedef __attribute__((ext_vector_type(8))) short short8;
typedef __attribute__((ext_vector_type(4))) float floatx4;
typedef unsigned short u16;
typedef unsigned int u32;

#define GLOAD_LDS16(gp, lp)                                                    \
  __builtin_amdgcn_global_load_lds(                                            \
      (const __attribute__((address_space(1))) u32*)(gp),                      \
      (__attribute__((address_space(3))) u32*)(lp), 16, 0, 0)

__device__ __forceinline__ float wsum(float v) {
#pragma unroll
  for (int m = 1; m < 64; m <<= 1) v += __shfl_xor(v, m, 64);
  return v;
}

__device__ __forceinline__ u32 bf16rn(float f) {
  u32 u = __float_as_uint(f);
  return (u + 0x7FFFu + ((u >> 16) & 1u)) >> 16;
}
__device__ __forceinline__ u32 pack2(float a, float b) {
  return bf16rn(a) | (bf16rn(b) << 16);
}
__device__ __forceinline__ float bf2f(u16 v) {
  return __uint_as_float(((u32)v) << 16);
}
__device__ __forceinline__ u32 cvtpk(float lo, float hi) {
  u32 r;
  asm volatile("v_cvt_pk_bf16_f32 %0, %1, %2" : "=v"(r) : "v"(lo), "v"(hi));
  return r;
}
// XOR swizzle for 512B-row tiles (bits 9-11 -> 4-6)
__device__ __forceinline__ u32 swz512(u32 b) { return b ^ (((b >> 9) & 7u) << 4); }

// ---- pack w1/Wb/Wt into MFMA-fragment-ordered bf16 + proj param table ----
// layout: [ktile][colTile(16)][lane(64)][e(8)];  k = ktile*32 + (lane>>4)*8 + e,
// col = colTile*16 + (lane&15)
__global__ __launch_bounds__(256)
void k_pack(const float* __restrict__ w1, const float* __restrict__ Wb,
            const float* __restrict__ Wt, const float* __restrict__ b1,
            const float* __restrict__ pg, const float* __restrict__ pbeta,
            const float* __restrict__ w2, u16* __restrict__ pk1,
            u16* __restrict__ pkb, u16* __restrict__ pkt,
            float4* __restrict__ pp) {
  int idx = blockIdx.x * 256 + threadIdx.x;
  if (idx < 32768) {                       // w1: K=128 padded from 107
    int e = idx & 7, lane = (idx >> 3) & 63, ct = (idx >> 9) & 15, kk = idx >> 13;
    int k = kk * 32 + (lane >> 4) * 8 + e, col = ct * 16 + (lane & 15);
    pk1[idx] = (u16)(k < kTA ? bf16rn(w1[(size_t)k * 256 + col]) : 0);
  } else if (idx < 163840) {
    int j = idx - 32768;
    const float* W = (j < 65536) ? Wb : Wt;
    u16* pk = (j < 65536) ? pkb : pkt;
    int t = j & 65535;
    int e = t & 7, lane = (t >> 3) & 63, ct = (t >> 9) & 15, kt = t >> 13;
    int k = kt * 32 + (lane >> 4) * 8 + e, col = ct * 16 + (lane & 15);
    pk[t] = (u16)bf16rn(W[(size_t)k * 256 + col]);
  } else if (idx < 163840 + 256) {
    int col = idx - 163840;
    pp[col] = make_float4(b1[col], pg[col], pbeta[col], w2[col]);
  }
}

// ---- fp32 -> bf16 convert (x -> xb), 8 elements/thread ----
__global__ __launch_bounds__(256)
void k_cvt(const float* __restrict__ in, u16* __restrict__ out) {
  size_t i = (size_t)(blockIdx.x * 256 + threadIdx.x) * 8;
  float4 a = *(const float4*)(in + i);
  float4 b = *(const float4*)(in + i + 4);
  uint4 o = make_uint4(pack2(a.x, a.y), pack2(a.z, a.w),
                       pack2(b.x, b.y), pack2(b.z, b.w));
  *(uint4*)(out + i) = o;
}

// ---- fused edge prep for both graphs: degree + count ----
__global__ __launch_bounds__(256)
void k_edge_prep_both(const int* __restrict__ bcol, const float* __restrict__ bw,
                      const int* __restrict__ tcol, const float* __restrict__ tw,
                      float* __restrict__ deg_b, int* __restrict__ cnt_b,
                      float* __restrict__ deg_t, int* __restrict__ cnt_t) {
  int e = blockIdx.x * 256 + threadIdx.x;
  if (e < kEB) {
    int c = bcol[e];
    atomicAdd(&deg_b[c], bw[e]);
    atomicAdd(&cnt_b[c], 1);
  } else {
    int t = e - kEB;
    int c = tcol[t];
    atomicAdd(&deg_t[c], tw[t]);
    atomicAdd(&cnt_t[c], 1);
  }
}

// ---- exclusive scan (one block per graph) ----
__global__ __launch_bounds__(256)
void k_scan_both(const int* __restrict__ cnt_b, int* __restrict__ base_b,
                 int* __restrict__ cur_b, const int* __restrict__ cnt_t,
                 int* __restrict__ base_t, int* __restrict__ cur_t) {
  const int* cnt = blockIdx.x ? cnt_t : cnt_b;
  int* base = blockIdx.x ? base_t : base_b;
  int* cur  = blockIdx.x ? cur_t : cur_b;
  __shared__ int part[256];
  int tid = threadIdx.x;
  int per = kN >> 8;
  int i0 = tid * per;
  int s = 0;
  for (int k = 0; k < per; ++k) s += cnt[i0 + k];
  part[tid] = s;
  __syncthreads();
  for (int off = 1; off < 256; off <<= 1) {
    int v = (tid >= off) ? part[tid - off] : 0;
    __syncthreads();
    part[tid] += v;
    __syncthreads();
  }
  int run = (tid == 0) ? 0 : part[tid - 1];
  for (int k = 0; k < per; ++k) {
    base[i0 + k] = run; cur[i0 + k] = run; run += cnt[i0 + k];
  }
  if (tid == 255) base[kN] = run;
}

__global__ __launch_bounds__(256)
void k_dis_both(const float* __restrict__ deg_b, float* __restrict__ dis_b,
                const float* __restrict__ deg_t, float* __restrict__ dis_t) {
  int i = blockIdx.x * 256 + threadIdx.x;
  if (i < kN) {
    float d = deg_b[i] + 1.0f;
    dis_b[i] = (d > 0.f) ? rsqrtf(d) : 0.f;
  } else {
    int t = i - kN;
    float d = deg_t[t] + 1.0f;
    dis_t[t] = (d > 0.f) ? rsqrtf(d) : 0.f;
  }
}

// ---- CSR fill for both graphs: per edge store (src, norm) packed ----
__global__ __launch_bounds__(256)
void k_fill_both(const int* __restrict__ bei, const float* __restrict__ bw,
                 const float* __restrict__ dis_b, int* __restrict__ cur_b,
                 int2* __restrict__ csr_b, const int* __restrict__ tei,
                 const float* __restrict__ tw, const float* __restrict__ dis_t,
                 int* __restrict__ cur_t, int2* __restrict__ csr_t) {
  int e = blockIdx.x * 256 + threadIdx.x;
  if (e < kEB) {
    int r = bei[e], c = bei[kEB + e];
    float nrm = dis_b[r] * bw[e] * dis_b[c];
    int pos = atomicAdd(&cur_b[c], 1);
    csr_b[pos] = make_int2(r, __float_as_int(nrm));
  } else {
    int t = e - kEB;
    int r = tei[t], c = tei[kET + t];
    float nrm = dis_t[r] * tw[t] * dis_t[c];
    int pos = atomicAdd(&cur_t[c], 1);
    csr_t[pos] = make_int2(r, __float_as_int(nrm));
  }
}

// ---- bf16-MFMA GEMM: Cb[M,256] = Ab[M,256] @ W, all bf16 (fp32 accum) ----
// 32 rows/block, 4 waves x 64 cols, packed W fragments, A via global_load_lds.
__global__ __launch_bounds__(256)
void k_gemm_mfma(const u16* __restrict__ Ab, const u16* __restrict__ pkW,
                 u16* __restrict__ Cb) {
  __shared__ __align__(16) u16 Atile[32 * 256];   // 16 KB, swizzled (512B rows)
  int tid = threadIdx.x;
  int w = tid >> 6, lane = tid & 63, low4 = lane & 15, hi = lane >> 4;
  int row0 = blockIdx.x * 32;

  const char* asrc = (const char*)(Ab + (size_t)row0 * 256);
#pragma unroll
  for (int i = 0; i < 4; ++i) {
    u32 d = (u32)(((i * 4 + w) * 64 + lane) * 16);
    GLOAD_LDS16(asrc + swz512(d), (char*)Atile + (i * 4 + w) * 1024);
  }

  floatx4 acc[2][4];
#pragma unroll
  for (int rt = 0; rt < 2; ++rt)
#pragma unroll
    for (int nn = 0; nn < 4; ++nn) acc[rt][nn] = (floatx4){0.f, 0.f, 0.f, 0.f};

  __syncthreads();   // drains vmcnt -> A tile ready

#pragma unroll
  for (int kt = 0; kt < 8; ++kt) {
    short8 bfr[4];
    const u16* pw = pkW + ((size_t)(kt * 16 + w * 4) * 64 + lane) * 8;
#pragma unroll
    for (int nn = 0; nn < 4; ++nn) bfr[nn] = *(const short8*)(pw + nn * 512);
    short8 afr[2];
#pragma unroll
    for (int rt = 0; rt < 2; ++rt) {
      u32 p = (u32)((rt * 16 + low4) * 512 + (kt * 32 + hi * 8) * 2);
      afr[rt] = *(const short8*)((const char*)Atile + swz512(p));
    }
#pragma unroll
    for (int rt = 0; rt < 2; ++rt)
#pragma unroll
      for (int nn = 0; nn < 4; ++nn)
        acc[rt][nn] = __builtin_amdgcn_mfma_f32_16x16x32_bf16(afr[rt], bfr[nn],
                                                              acc[rt][nn], 0, 0, 0);
  }
#pragma unroll
  for (int rt = 0; rt < 2; ++rt)
#pragma unroll
    for (int nn = 0; nn < 4; ++nn)
#pragma unroll
      for (int j = 0; j < 4; ++j) {
        int row = row0 + rt * 16 + hi * 4 + j;
        int col = w * 64 + nn * 16 + low4;
        Cb[(size_t)row * 256 + col] = (u16)bf16rn(acc[rt][nn][j]);
      }
}

// ---- temporal edge MLP via MFMA ----
// 64 edges/block; wave w owns rows [w*16, w*16+16) x all 256 cols (acc[16]).
// fp32 attr staged linearly via global_load_lds; A-frag built once per wave;
// LN fully wave-local (shfl over low4), no epilogue barriers.
__global__ __launch_bounds__(256)
void k_proj_mfma(const float* __restrict__ attr, const u16* __restrict__ pk1,
                 const float4* __restrict__ pp, const float* __restrict__ b2,
                 float* __restrict__ temp_w) {
  __shared__ __align__(16) float Af[64 * kTA + 32];   // +32 pad: safe speculation
  int tid = threadIdx.x;
  int w = tid >> 6, lane = tid & 63, low4 = lane & 15, hi = lane >> 4;
  int e0 = blockIdx.x * 64;

  // stage 64*107 fp32 = 1712 aligned 16B chunks, linear copy, async
  const char* src = (const char*)(attr + (size_t)e0 * kTA);
#pragma unroll
  for (int it = 0; it < 7; ++it) {
    int idx = it * 256 + tid;
    if (idx < 1712)
      GLOAD_LDS16(src + (size_t)idx * 16, (char*)Af + (it * 256 + w * 64) * 16);
  }

  floatx4 acc[16];
#pragma unroll
  for (int nn = 0; nn < 16; ++nn) acc[nn] = (floatx4){0.f, 0.f, 0.f, 0.f};

  __syncthreads();   // drains vmcnt -> attr tile ready

  int rowbase = w * 16;
#pragma unroll
  for (int kk = 0; kk < 4; ++kk) {
    // A fragment: row = rowbase + low4, k = kk*32 + hi*8 + e
    int r = rowbase + low4;
    int kb = kk * 32 + hi * 8;
    const float* rowp = Af + r * kTA + kb;
    float v[8];
#pragma unroll
    for (int e = 0; e < 8; ++e)
      v[e] = (kk == 3 && kb + e >= kTA) ? 0.f : rowp[e];
    union { short8 s8; uint4 u4; } fr;
    fr.u4 = make_uint4(cvtpk(v[0], v[1]), cvtpk(v[2], v[3]),
                       cvtpk(v[4], v[5]), cvtpk(v[6], v[7]));
    const u16* pwbase = pk1 + ((size_t)(kk * 16) * 64 + lane) * 8;
#pragma unroll
    for (int nn = 0; nn < 16; ++nn) {
      short8 bfr = *(const short8*)(pwbase + nn * 512);
      acc[nn] = __builtin_amdgcn_mfma_f32_16x16x32_bf16(fr.s8, bfr, acc[nn], 0, 0, 0);
    }
  }

  // per-lane params for its 16 cols (col = nn*16 + low4): (b1, g, beta, w2)
  float4 ppv[16];
#pragma unroll
  for (int nn = 0; nn < 16; ++nn) ppv[nn] = pp[nn * 16 + low4];
  float b2s = b2[0];

  // epilogue: rows rowbase + hi*4 + j; row data = 16 lanes sharing hi,
  // each lane holding 16 nn channels.
#pragma unroll
  for (int j = 0; j < 4; ++j) {
    float s1 = 0.f, s2 = 0.f;
#pragma unroll
    for (int nn = 0; nn < 16; ++nn) {
      float hv = acc[nn][j] + ppv[nn].x;
      s1 += hv; s2 += hv * hv;
    }
#pragma unroll
    for (int m = 1; m < 16; m <<= 1) {
      s1 += __shfl_xor(s1, m, 64);
      s2 += __shfl_xor(s2, m, 64);
    }
    float mean = s1 * (1.f / 256);
    float inv = rsqrtf(s2 * (1.f / 256) - mean * mean + kEps);
    float d = 0.f;
#pragma unroll
    for (int nn = 0; nn < 16; ++nn) {
      float hv = acc[nn][j] + ppv[nn].x;
      float y = fmaxf((hv - mean) * inv * ppv[nn].y + ppv[nn].z, 0.f);
      d += y * ppv[nn].w;
    }
#pragma unroll
    for (int m = 1; m < 16; m <<= 1) d += __shfl_xor(d, m, 64);
    if (low4 == 0) temp_w[e0 + rowbase + hi * 4 + j] = d + b2s;
  }
}

// ---- fused gather-aggregate (bf16 h) + bias + residual + LN + relu ----
// FINAL=0: resid fp32 (x), out bf16 (sb). FINAL=1: resid bf16 (sb), out fp32.
template <int FINAL>
__global__ __launch_bounds__(256)
void k_agg_ln(const u16* __restrict__ h, const void* __restrict__ residv,
              const float* __restrict__ x0, const int2* __restrict__ csr,
              const int* __restrict__ basep, const float* __restrict__ dis,
              const float* __restrict__ bias, const float* __restrict__ g1,
              const float* __restrict__ b1, const float* __restrict__ g2,
              const float* __restrict__ b2, void* __restrict__ outv) {
  int wave = threadIdx.x >> 6, lane = threadIdx.x & 63;
  int node = (blockIdx.x << 2) + wave;
  int c = lane << 2;
  float di = dis[node];
  ushort4 hs = *(const ushort4*)(h + (size_t)node * HN + c);
  float sl = di * di;
  float4 acc = make_float4(bf2f(hs.x) * sl, bf2f(hs.y) * sl,
                           bf2f(hs.z) * sl, bf2f(hs.w) * sl);
  int e0 = basep[node], e1 = basep[node + 1];
  if (e0 < e1) {
    int2 p = csr[e0];
    for (int k = e0; k < e1; ++k) {
      int2 pn = p;
      if (k + 1 < e1) pn = csr[k + 1];
      float nrm = __int_as_float(p.y);
      ushort4 hv = *(const ushort4*)(h + (size_t)p.x * HN + c);
      acc.x += nrm * bf2f(hv.x); acc.y += nrm * bf2f(hv.y);
      acc.z += nrm * bf2f(hv.z); acc.w += nrm * bf2f(hv.w);
      p = pn;
    }
  }
  float4 bb = *(const float4*)(bias + c);
  float4 rr;
  if (!FINAL) {
    rr = *(const float4*)((const float*)residv + (size_t)node * HN + c);
  } else {
    ushort4 rv = *(const ushort4*)((const u16*)residv + (size_t)node * HN + c);
    rr = make_float4(bf2f(rv.x), bf2f(rv.y), bf2f(rv.z), bf2f(rv.w));
  }
  float v0 = acc.x + bb.x + rr.x;
  float v1 = acc.y + bb.y + rr.y;
  float v2 = acc.z + bb.z + rr.z;
  float v3 = acc.w + bb.w + rr.w;
  float sum = wsum(v0 + v1 + v2 + v3);
  float ss  = wsum(v0 * v0 + v1 * v1 + v2 * v2 + v3 * v3);
  float mean = sum * (1.f / HN);
  float inv = rsqrtf(ss * (1.f / HN) - mean * mean + kEps);
  float4 g = *(const float4*)(g1 + c);
  float4 b = *(const float4*)(b1 + c);
  float y0 = fmaxf((v0 - mean) * inv * g.x + b.x, 0.f);
  float y1 = fmaxf((v1 - mean) * inv * g.y + b.y, 0.f);
  float y2 = fmaxf((v2 - mean) * inv * g.z + b.z, 0.f);
  float y3 = fmaxf((v3 - mean) * inv * g.w + b.w, 0.f);
  if (!FINAL) {
    uint2 o = make_uint2(pack2(y0, y1), pack2(y2, y3));
    *(uint2*)((u16*)outv + (size_t)node * HN + c) = o;
  } else {
    float4 xx = *(const float4*)(x0 + (size_t)node * HN + c);
    float z0 = y0 + xx.x, z1 = y1 + xx.y, z2 = y2 + xx.z, z3 = y3 + xx.w;
    float s2 = wsum(z0 + z1 + z2 + z3);
    float q2 = wsum(z0 * z0 + z1 * z1 + z2 * z2 + z3 * z3);
    float m2 = s2 * (1.f / HN);
    float i2 = rsqrtf(q2 * (1.f / HN) - m2 * m2 + kEps);
    float4 G = *(const float4*)(g2 + c);
    float4 B = *(const float4*)(b2 + c);
    float4 o = make_float4((z0 - m2) * i2 * G.x + B.x, (z1 - m2) * i2 * G.y + B.y,
                           (z2 - m2) * i2 * G.z + B.z, (z3 - m2) * i2 * G.w + B.w);
    *(float4*)((float*)outv + (size_t)node * HN + c) = o;
  }
}

extern "C" void kernel_launch(void* const* d_in, const int* in_sizes, int n_in,
                              void* d_out, int out_size, void* d_ws, size_t ws_size,
                              hipStream_t stream) {
  const float* x     = (const float*)d_in[0];
  const int*   bei   = (const int*)d_in[1];
  const float* bew   = (const float*)d_in[2];
  const int*   tei   = (const int*)d_in[3];
  const float* tattr = (const float*)d_in[4];
  const float* Wb    = (const float*)d_in[5];
  const float* bb    = (const float*)d_in[6];
  const float* Wt    = (const float*)d_in[7];
  const float* bt    = (const float*)d_in[8];
  const float* gs    = (const float*)d_in[9];
  const float* bs    = (const float*)d_in[10];
  const float* gt    = (const float*)d_in[11];
  const float* btn   = (const float*)d_in[12];
  const float* pw1   = (const float*)d_in[13];
  const float* pb1   = (const float*)d_in[14];
  const float* pg    = (const float*)d_in[15];
  const float* pbeta = (const float*)d_in[16];
  const float* pw2   = (const float*)d_in[17];
  const float* pb2   = (const float*)d_in[18];
  float* outp = (float*)d_out;

  size_t off = 0;
  auto alloc = [&](size_t bytes) -> void* {
    void* p = (char*)d_ws + off;
    off += (bytes + 255) & ~(size_t)255;
    return p;
  };
  float* deg_b = (float*)alloc(kN * 4);
  float* deg_t = (float*)alloc(kN * 4);
  int*   cnt_b = (int*)alloc(kN * 4);
  int*   cnt_t = (int*)alloc(kN * 4);       // deg_b..cnt_t contiguous: one memset
  float* dis_b = (float*)alloc(kN * 4);
  float* dis_t = (float*)alloc(kN * 4);
  int*   base_b = (int*)alloc((kN + 1) * 4);
  int*   base_t = (int*)alloc((kN + 1) * 4);
  int*   cur_b  = (int*)alloc(kN * 4);
  int*   cur_t  = (int*)alloc(kN * 4);
  float* tmpw   = (float*)alloc(kET * 4);
  int2*  csr_b  = (int2*)alloc((size_t)kEB * 8);
  int2*  csr_t  = (int2*)alloc((size_t)kET * 8);
  u16*   pk1 = (u16*)alloc(32768 * 2);
  u16*   pkb = (u16*)alloc(65536 * 2);
  u16*   pkt = (u16*)alloc(65536 * 2);
  float4* pp = (float4*)alloc(256 * 16);
  u16*   xb  = (u16*)alloc((size_t)kN * HN * 2);
  u16*   hb  = (u16*)alloc((size_t)kN * HN * 2);
  u16*   sb  = (u16*)alloc((size_t)kN * HN * 2);
  (void)ws_size; (void)in_sizes; (void)n_in; (void)out_size;

  hipMemsetAsync(deg_b, 0, (size_t)4 * kN * 4, stream);

  // const prep
  k_pack<<<641, 256, 0, stream>>>(pw1, Wb, Wt, pb1, pg, pbeta, pw2,
                                  pk1, pkb, pkt, pp);
  k_cvt<<<kN * HN / 8 / 256, 256, 0, stream>>>(x, xb);

  // temporal edge weights (independent of node pipeline)
  k_proj_mfma<<<kET / 64, 256, 0, stream>>>(tattr, pk1, pp, pb2, tmpw);

  // graph structure for both graphs
  k_edge_prep_both<<<(kEB + kET) / 256, 256, 0, stream>>>(
      bei + kEB, bew, tei + kET, tmpw, deg_b, cnt_b, deg_t, cnt_t);
  k_scan_both<<<2, 256, 0, stream>>>(cnt_b, base_b, cur_b, cnt_t, base_t, cur_t);
  k_dis_both<<<2 * kN / 256, 256, 0, stream>>>(deg_b, dis_b, deg_t, dis_t);
  k_fill_both<<<(kEB + kET) / 256, 256, 0, stream>>>(
      bei, bew, dis_b, cur_b, csr_b, tei, tmpw, dis_t, cur_t, csr_t);

  // stage 1: bold GCN
  k_gemm_mfma<<<kN / 32, 256, 0, stream>>>(xb, pkb, hb);
  k_agg_ln<0><<<kN / 4, 256, 0, stream>>>(hb, x, nullptr, csr_b, base_b, dis_b,
                                          bb, gs, bs, nullptr, nullptr, sb);
  // stage 2: temporal GCN + final LN
  k_gemm_mfma<<<kN / 32, 256, 0, stream>>>(sb, pkt, hb);
  k_agg_ln<1><<<kN / 4, 256, 0, stream>>>(hb, sb, x, csr_t, base_t, dis_t,
                                          bt, gt, btn, gs, bs, outp);
}

// Round 6
// 317.073 us; speedup vs baseline: 1.0658x; 1.0658x over previous
//
#include <hip/hip_runtime.h>

constexpr int kN  = 16384;
constexpr int kEB = 524288;
constexpr int kET = 262144;
constexpr int kTA = 107;
constexpr float kEps = 1e-5f;
#define HN 256

typedef __attribute__((ext_vector_type(8))) short short8;
typedef __attribute__((ext_vector_type(4))) float floatx4;
typedef unsigned short u16;
typedef unsigned int u32;

#define GLOAD_LDS16(gp, lp)                                                    \
  __builtin_amdgcn_global_load_lds(                                            \
      (const __attribute__((address_space(1))) u32*)(gp),                      \
      (__attribute__((address_space(3))) u32*)(lp), 16, 0, 0)

__device__ __forceinline__ float wsum(float v) {
#pragma unroll
  for (int m = 1; m < 64; m <<= 1) v += __shfl_xor(v, m, 64);
  return v;
}

__device__ __forceinline__ u32 bf16rn(float f) {
  u32 u = __float_as_uint(f);
  return (u + 0x7FFFu + ((u >> 16) & 1u)) >> 16;
}
__device__ __forceinline__ u32 pack2(float a, float b) {
  return bf16rn(a) | (bf16rn(b) << 16);
}
__device__ __forceinline__ float bf2f(u16 v) {
  return __uint_as_float(((u32)v) << 16);
}
__device__ __forceinline__ u32 cvtpk(float lo, float hi) {
  u32 r;
  asm("v_cvt_pk_bf16_f32 %0, %1, %2" : "=v"(r) : "v"(lo), "v"(hi));
  return r;
}
// XOR swizzle for 512B-row tiles (bits 9-11 -> 4-6)
__device__ __forceinline__ u32 swz512(u32 b) { return b ^ (((b >> 9) & 7u) << 4); }

// ---- pack w1/Wb/Wt into MFMA-fragment-ordered bf16 + proj param table ----
// layout: [ktile][colTile(16)][lane(64)][e(8)];  k = ktile*32 + (lane>>4)*8 + e,
// col = colTile*16 + (lane&15)
__global__ __launch_bounds__(256)
void k_pack(const float* __restrict__ w1, const float* __restrict__ Wb,
            const float* __restrict__ Wt, const float* __restrict__ b1,
            const float* __restrict__ pg, const float* __restrict__ pbeta,
            const float* __restrict__ w2, u16* __restrict__ pk1,
            u16* __restrict__ pkb, u16* __restrict__ pkt,
            float4* __restrict__ pp) {
  int idx = blockIdx.x * 256 + threadIdx.x;
  if (idx < 32768) {                       // w1: K=128 padded from 107
    int e = idx & 7, lane = (idx >> 3) & 63, ct = (idx >> 9) & 15, kk = idx >> 13;
    int k = kk * 32 + (lane >> 4) * 8 + e, col = ct * 16 + (lane & 15);
    pk1[idx] = (u16)(k < kTA ? bf16rn(w1[(size_t)k * 256 + col]) : 0);
  } else if (idx < 163840) {
    int j = idx - 32768;
    const float* W = (j < 65536) ? Wb : Wt;
    u16* pk = (j < 65536) ? pkb : pkt;
    int t = j & 65535;
    int e = t & 7, lane = (t >> 3) & 63, ct = (t >> 9) & 15, kt = t >> 13;
    int k = kt * 32 + (lane >> 4) * 8 + e, col = ct * 16 + (lane & 15);
    pk[t] = (u16)bf16rn(W[(size_t)k * 256 + col]);
  } else if (idx < 163840 + 256) {
    int col = idx - 163840;
    pp[col] = make_float4(b1[col], pg[col], pbeta[col], w2[col]);
  }
}

// ---- fp32 -> bf16 convert (x -> xb), 8 elements/thread ----
__global__ __launch_bounds__(256)
void k_cvt(const float* __restrict__ in, u16* __restrict__ out) {
  size_t i = (size_t)(blockIdx.x * 256 + threadIdx.x) * 8;
  float4 a = *(const float4*)(in + i);
  float4 b = *(const float4*)(in + i + 4);
  uint4 o = make_uint4(pack2(a.x, a.y), pack2(a.z, a.w),
                       pack2(b.x, b.y), pack2(b.z, b.w));
  *(uint4*)(out + i) = o;
}

// ---- fused edge prep for both graphs: degree + count ----
__global__ __launch_bounds__(256)
void k_edge_prep_both(const int* __restrict__ bcol, const float* __restrict__ bw,
                      const int* __restrict__ tcol, const float* __restrict__ tw,
                      float* __restrict__ deg_b, int* __restrict__ cnt_b,
                      float* __restrict__ deg_t, int* __restrict__ cnt_t) {
  int e = blockIdx.x * 256 + threadIdx.x;
  if (e < kEB) {
    int c = bcol[e];
    atomicAdd(&deg_b[c], bw[e]);
    atomicAdd(&cnt_b[c], 1);
  } else {
    int t = e - kEB;
    int c = tcol[t];
    atomicAdd(&deg_t[c], tw[t]);
    atomicAdd(&cnt_t[c], 1);
  }
}

// ---- exclusive scan (one block per graph) ----
__global__ __launch_bounds__(256)
void k_scan_both(const int* __restrict__ cnt_b, int* __restrict__ base_b,
                 int* __restrict__ cur_b, const int* __restrict__ cnt_t,
                 int* __restrict__ base_t, int* __restrict__ cur_t) {
  const int* cnt = blockIdx.x ? cnt_t : cnt_b;
  int* base = blockIdx.x ? base_t : base_b;
  int* cur  = blockIdx.x ? cur_t : cur_b;
  __shared__ int part[256];
  int tid = threadIdx.x;
  int per = kN >> 8;
  int i0 = tid * per;
  int s = 0;
  for (int k = 0; k < per; ++k) s += cnt[i0 + k];
  part[tid] = s;
  __syncthreads();
  for (int off = 1; off < 256; off <<= 1) {
    int v = (tid >= off) ? part[tid - off] : 0;
    __syncthreads();
    part[tid] += v;
    __syncthreads();
  }
  int run = (tid == 0) ? 0 : part[tid - 1];
  for (int k = 0; k < per; ++k) {
    base[i0 + k] = run; cur[i0 + k] = run; run += cnt[i0 + k];
  }
  if (tid == 255) base[kN] = run;
}

__global__ __launch_bounds__(256)
void k_dis_both(const float* __restrict__ deg_b, float* __restrict__ dis_b,
                const float* __restrict__ deg_t, float* __restrict__ dis_t) {
  int i = blockIdx.x * 256 + threadIdx.x;
  if (i < kN) {
    float d = deg_b[i] + 1.0f;
    dis_b[i] = (d > 0.f) ? rsqrtf(d) : 0.f;
  } else {
    int t = i - kN;
    float d = deg_t[t] + 1.0f;
    dis_t[t] = (d > 0.f) ? rsqrtf(d) : 0.f;
  }
}

// ---- CSR fill for both graphs: per edge store (src, norm) packed ----
__global__ __launch_bounds__(256)
void k_fill_both(const int* __restrict__ bei, const float* __restrict__ bw,
                 const float* __restrict__ dis_b, int* __restrict__ cur_b,
                 int2* __restrict__ csr_b, const int* __restrict__ tei,
                 const float* __restrict__ tw, const float* __restrict__ dis_t,
                 int* __restrict__ cur_t, int2* __restrict__ csr_t) {
  int e = blockIdx.x * 256 + threadIdx.x;
  if (e < kEB) {
    int r = bei[e], c = bei[kEB + e];
    float nrm = dis_b[r] * bw[e] * dis_b[c];
    int pos = atomicAdd(&cur_b[c], 1);
    csr_b[pos] = make_int2(r, __float_as_int(nrm));
  } else {
    int t = e - kEB;
    int r = tei[t], c = tei[kET + t];
    float nrm = dis_t[r] * tw[t] * dis_t[c];
    int pos = atomicAdd(&cur_t[c], 1);
    csr_t[pos] = make_int2(r, __float_as_int(nrm));
  }
}

// ---- bf16-MFMA GEMM: Cb[M,256] = Ab[M,256] @ W, all bf16 (fp32 accum) ----
// 32 rows/block, 4 waves x 64 cols, packed W fragments, A via global_load_lds.
__global__ __launch_bounds__(256)
void k_gemm_mfma(const u16* __restrict__ Ab, const u16* __restrict__ pkW,
                 u16* __restrict__ Cb) {
  __shared__ __align__(16) u16 Atile[32 * 256];   // 16 KB, swizzled (512B rows)
  int tid = threadIdx.x;
  int w = tid >> 6, lane = tid & 63, low4 = lane & 15, hi = lane >> 4;
  int row0 = blockIdx.x * 32;

  const char* asrc = (const char*)(Ab + (size_t)row0 * 256);
#pragma unroll
  for (int i = 0; i < 4; ++i) {
    u32 d = (u32)(((i * 4 + w) * 64 + lane) * 16);
    GLOAD_LDS16(asrc + swz512(d), (char*)Atile + (i * 4 + w) * 1024);
  }

  floatx4 acc[2][4];
#pragma unroll
  for (int rt = 0; rt < 2; ++rt)
#pragma unroll
    for (int nn = 0; nn < 4; ++nn) acc[rt][nn] = (floatx4){0.f, 0.f, 0.f, 0.f};

  __syncthreads();   // drains vmcnt -> A tile ready

#pragma unroll
  for (int kt = 0; kt < 8; ++kt) {
    short8 bfr[4];
    const u16* pw = pkW + ((size_t)(kt * 16 + w * 4) * 64 + lane) * 8;
#pragma unroll
    for (int nn = 0; nn < 4; ++nn) bfr[nn] = *(const short8*)(pw + nn * 512);
    short8 afr[2];
#pragma unroll
    for (int rt = 0; rt < 2; ++rt) {
      u32 p = (u32)((rt * 16 + low4) * 512 + (kt * 32 + hi * 8) * 2);
      afr[rt] = *(const short8*)((const char*)Atile + swz512(p));
    }
#pragma unroll
    for (int rt = 0; rt < 2; ++rt)
#pragma unroll
      for (int nn = 0; nn < 4; ++nn)
        acc[rt][nn] = __builtin_amdgcn_mfma_f32_16x16x32_bf16(afr[rt], bfr[nn],
                                                              acc[rt][nn], 0, 0, 0);
  }
#pragma unroll
  for (int rt = 0; rt < 2; ++rt)
#pragma unroll
    for (int nn = 0; nn < 4; ++nn)
#pragma unroll
      for (int j = 0; j < 4; ++j) {
        int row = row0 + rt * 16 + hi * 4 + j;
        int col = w * 64 + nn * 16 + low4;
        Cb[(size_t)row * 256 + col] = (u16)bf16rn(acc[rt][nn][j]);
      }
}

// ---- temporal edge MLP via MFMA, no LDS, no barriers ----
// Wave w owns edges [blk*64 + w*16, +16) x all 256 cols. A-fragments loaded
// directly from global (27 indep dwords/lane); nn-outer loop keeps one acc
// live; hv packed to bf16 (LN stats fp32) -> low VGPR, high occupancy.
__global__ __launch_bounds__(256, 4)
void k_proj_mfma(const float* __restrict__ attr, const u16* __restrict__ pk1,
                 const float* __restrict__ b1, const float4* __restrict__ pp,
                 const float* __restrict__ b2, float* __restrict__ temp_w) {
  int tid = threadIdx.x;
  int w = tid >> 6, lane = tid & 63, low4 = lane & 15, hi = lane >> 4;
  int e0 = blockIdx.x * 64 + w * 16;
  const float* rowp = attr + (size_t)(e0 + low4) * kTA;

  // A fragments: row = low4, k = kk*32 + hi*8 + e (zero-pad k >= 107)
  short8 a[4];
#pragma unroll
  for (int kk = 0; kk < 4; ++kk) {
    int kb = kk * 32 + hi * 8;
    float v[8];
#pragma unroll
    for (int e = 0; e < 8; ++e)
      v[e] = (kk < 3 || kb + e < kTA) ? rowp[kb + e] : 0.f;
    union { short8 s8; uint4 u4; } fr;
    fr.u4 = make_uint4(cvtpk(v[0], v[1]), cvtpk(v[2], v[3]),
                       cvtpk(v[4], v[5]), cvtpk(v[6], v[7]));
    a[kk] = fr.s8;
  }

  u32 hvpk[16][2];
  float s1[4] = {0.f, 0.f, 0.f, 0.f}, s2[4] = {0.f, 0.f, 0.f, 0.f};
#pragma unroll
  for (int nn = 0; nn < 16; ++nn) {
    floatx4 acc = (floatx4){0.f, 0.f, 0.f, 0.f};
#pragma unroll
    for (int kk = 0; kk < 4; ++kk) {
      short8 bfr = *(const short8*)(pk1 + ((size_t)(kk * 16 + nn) * 64 + lane) * 8);
      acc = __builtin_amdgcn_mfma_f32_16x16x32_bf16(a[kk], bfr, acc, 0, 0, 0);
    }
    float b1v = b1[nn * 16 + low4];
    float h0 = acc[0] + b1v, h1 = acc[1] + b1v, h2 = acc[2] + b1v, h3 = acc[3] + b1v;
    s1[0] += h0; s2[0] += h0 * h0;
    s1[1] += h1; s2[1] += h1 * h1;
    s1[2] += h2; s2[2] += h2 * h2;
    s1[3] += h3; s2[3] += h3 * h3;
    hvpk[nn][0] = cvtpk(h0, h1);
    hvpk[nn][1] = cvtpk(h2, h3);
  }

  // per-row LN stats: reduce over the 16 low4 lanes
  float mean[4], inv[4];
#pragma unroll
  for (int j = 0; j < 4; ++j) {
#pragma unroll
    for (int m = 1; m < 16; m <<= 1) {
      s1[j] += __shfl_xor(s1[j], m, 64);
      s2[j] += __shfl_xor(s2[j], m, 64);
    }
    mean[j] = s1[j] * (1.f / 256);
    inv[j] = rsqrtf(s2[j] * (1.f / 256) - mean[j] * mean[j] + kEps);
  }

  // y = relu(LN(hv)); d_j = sum_cols y * w2
  float d[4] = {0.f, 0.f, 0.f, 0.f};
#pragma unroll
  for (int nn = 0; nn < 16; ++nn) {
    float4 p = pp[nn * 16 + low4];   // (b1, g, beta, w2)
    float h0 = bf2f((u16)(hvpk[nn][0] & 0xFFFF));
    float h1 = bf2f((u16)(hvpk[nn][0] >> 16));
    float h2 = bf2f((u16)(hvpk[nn][1] & 0xFFFF));
    float h3 = bf2f((u16)(hvpk[nn][1] >> 16));
    d[0] += fmaxf((h0 - mean[0]) * inv[0] * p.y + p.z, 0.f) * p.w;
    d[1] += fmaxf((h1 - mean[1]) * inv[1] * p.y + p.z, 0.f) * p.w;
    d[2] += fmaxf((h2 - mean[2]) * inv[2] * p.y + p.z, 0.f) * p.w;
    d[3] += fmaxf((h3 - mean[3]) * inv[3] * p.y + p.z, 0.f) * p.w;
  }
  float b2s = b2[0];
#pragma unroll
  for (int j = 0; j < 4; ++j) {
#pragma unroll
    for (int m = 1; m < 16; m <<= 1) d[j] += __shfl_xor(d[j], m, 64);
    if (low4 == 0) temp_w[e0 + hi * 4 + j] = d[j] + b2s;
  }
}

// ---- fused gather-aggregate (bf16 h) + bias + residual + LN + relu ----
// FINAL=0: resid fp32 (x), out bf16 (sb). FINAL=1: resid bf16 (sb), out fp32.
template <int FINAL>
__global__ __launch_bounds__(256)
void k_agg_ln(const u16* __restrict__ h, const void* __restrict__ residv,
              const float* __restrict__ x0, const int2* __restrict__ csr,
              const int* __restrict__ basep, const float* __restrict__ dis,
              const float* __restrict__ bias, const float* __restrict__ g1,
              const float* __restrict__ b1, const float* __restrict__ g2,
              const float* __restrict__ b2, void* __restrict__ outv) {
  int wave = threadIdx.x >> 6, lane = threadIdx.x & 63;
  int node = (blockIdx.x << 2) + wave;
  int c = lane << 2;
  float di = dis[node];
  ushort4 hs = *(const ushort4*)(h + (size_t)node * HN + c);
  float sl = di * di;
  float4 acc = make_float4(bf2f(hs.x) * sl, bf2f(hs.y) * sl,
                           bf2f(hs.z) * sl, bf2f(hs.w) * sl);
  int e0 = basep[node], e1 = basep[node + 1];
  if (e0 < e1) {
    int2 p = csr[e0];
    for (int k = e0; k < e1; ++k) {
      int2 pn = p;
      if (k + 1 < e1) pn = csr[k + 1];
      float nrm = __int_as_float(p.y);
      ushort4 hv = *(const ushort4*)(h + (size_t)p.x * HN + c);
      acc.x += nrm * bf2f(hv.x); acc.y += nrm * bf2f(hv.y);
      acc.z += nrm * bf2f(hv.z); acc.w += nrm * bf2f(hv.w);
      p = pn;
    }
  }
  float4 bb = *(const float4*)(bias + c);
  float4 rr;
  if (!FINAL) {
    rr = *(const float4*)((const float*)residv + (size_t)node * HN + c);
  } else {
    ushort4 rv = *(const ushort4*)((const u16*)residv + (size_t)node * HN + c);
    rr = make_float4(bf2f(rv.x), bf2f(rv.y), bf2f(rv.z), bf2f(rv.w));
  }
  float v0 = acc.x + bb.x + rr.x;
  float v1 = acc.y + bb.y + rr.y;
  float v2 = acc.z + bb.z + rr.z;
  float v3 = acc.w + bb.w + rr.w;
  float sum = wsum(v0 + v1 + v2 + v3);
  float ss  = wsum(v0 * v0 + v1 * v1 + v2 * v2 + v3 * v3);
  float mean = sum * (1.f / HN);
  float inv = rsqrtf(ss * (1.f / HN) - mean * mean + kEps);
  float4 g = *(const float4*)(g1 + c);
  float4 b = *(const float4*)(b1 + c);
  float y0 = fmaxf((v0 - mean) * inv * g.x + b.x, 0.f);
  float y1 = fmaxf((v1 - mean) * inv * g.y + b.y, 0.f);
  float y2 = fmaxf((v2 - mean) * inv * g.z + b.z, 0.f);
  float y3 = fmaxf((v3 - mean) * inv * g.w + b.w, 0.f);
  if (!FINAL) {
    uint2 o = make_uint2(pack2(y0, y1), pack2(y2, y3));
    *(uint2*)((u16*)outv + (size_t)node * HN + c) = o;
  } else {
    float4 xx = *(const float4*)(x0 + (size_t)node * HN + c);
    float z0 = y0 + xx.x, z1 = y1 + xx.y, z2 = y2 + xx.z, z3 = y3 + xx.w;
    float s2 = wsum(z0 + z1 + z2 + z3);
    float q2 = wsum(z0 * z0 + z1 * z1 + z2 * z2 + z3 * z3);
    float m2 = s2 * (1.f / HN);
    float i2 = rsqrtf(q2 * (1.f / HN) - m2 * m2 + kEps);
    float4 G = *(const float4*)(g2 + c);
    float4 B = *(const float4*)(b2 + c);
    float4 o = make_float4((z0 - m2) * i2 * G.x + B.x, (z1 - m2) * i2 * G.y + B.y,
                           (z2 - m2) * i2 * G.z + B.z, (z3 - m2) * i2 * G.w + B.w);
    *(float4*)((float*)outv + (size_t)node * HN + c) = o;
  }
}

extern "C" void kernel_launch(void* const* d_in, const int* in_sizes, int n_in,
                              void* d_out, int out_size, void* d_ws, size_t ws_size,
                              hipStream_t stream) {
  const float* x     = (const float*)d_in[0];
  const int*   bei   = (const int*)d_in[1];
  const float* bew   = (const float*)d_in[2];
  const int*   tei   = (const int*)d_in[3];
  const float* tattr = (const float*)d_in[4];
  const float* Wb    = (const float*)d_in[5];
  const float* bb    = (const float*)d_in[6];
  const float* Wt    = (const float*)d_in[7];
  const float* bt    = (const float*)d_in[8];
  const float* gs    = (const float*)d_in[9];
  const float* bs    = (const float*)d_in[10];
  const float* gt    = (const float*)d_in[11];
  const float* btn   = (const float*)d_in[12];
  const float* pw1   = (const float*)d_in[13];
  const float* pb1   = (const float*)d_in[14];
  const float* pg    = (const float*)d_in[15];
  const float* pbeta = (const float*)d_in[16];
  const float* pw2   = (const float*)d_in[17];
  const float* pb2   = (const float*)d_in[18];
  float* outp = (float*)d_out;

  size_t off = 0;
  auto alloc = [&](size_t bytes) -> void* {
    void* p = (char*)d_ws + off;
    off += (bytes + 255) & ~(size_t)255;
    return p;
  };
  float* deg_b = (float*)alloc(kN * 4);
  float* deg_t = (float*)alloc(kN * 4);
  int*   cnt_b = (int*)alloc(kN * 4);
  int*   cnt_t = (int*)alloc(kN * 4);       // deg_b..cnt_t contiguous: one memset
  float* dis_b = (float*)alloc(kN * 4);
  float* dis_t = (float*)alloc(kN * 4);
  int*   base_b = (int*)alloc((kN + 1) * 4);
  int*   base_t = (int*)alloc((kN + 1) * 4);
  int*   cur_b  = (int*)alloc(kN * 4);
  int*   cur_t  = (int*)alloc(kN * 4);
  float* tmpw   = (float*)alloc(kET * 4);
  int2*  csr_b  = (int2*)alloc((size_t)kEB * 8);
  int2*  csr_t  = (int2*)alloc((size_t)kET * 8);
  u16*   pk1 = (u16*)alloc(32768 * 2);
  u16*   pkb = (u16*)alloc(65536 * 2);
  u16*   pkt = (u16*)alloc(65536 * 2);
  float4* pp = (float4*)alloc(256 * 16);
  u16*   xb  = (u16*)alloc((size_t)kN * HN * 2);
  u16*   hb  = (u16*)alloc((size_t)kN * HN * 2);
  u16*   sb  = (u16*)alloc((size_t)kN * HN * 2);
  (void)ws_size; (void)in_sizes; (void)n_in; (void)out_size;

  hipMemsetAsync(deg_b, 0, (size_t)4 * kN * 4, stream);

  // const prep
  k_pack<<<641, 256, 0, stream>>>(pw1, Wb, Wt, pb1, pg, pbeta, pw2,
                                  pk1, pkb, pkt, pp);
  k_cvt<<<kN * HN / 8 / 256, 256, 0, stream>>>(x, xb);

  // temporal edge weights (independent of node pipeline)
  k_proj_mfma<<<kET / 64, 256, 0, stream>>>(tattr, pk1, pb1, pp, pb2, tmpw);

  // graph structure for both graphs
  k_edge_prep_both<<<(kEB + kET) / 256, 256, 0, stream>>>(
      bei + kEB, bew, tei + kET, tmpw, deg_b, cnt_b, deg_t, cnt_t);
  k_scan_both<<<2, 256, 0, stream>>>(cnt_b, base_b, cur_b, cnt_t, base_t, cur_t);
  k_dis_both<<<2 * kN / 256, 256, 0, stream>>>(deg_b, dis_b, deg_t, dis_t);
  k_fill_both<<<(kEB + kET) / 256, 256, 0, stream>>>(
      bei, bew, dis_b, cur_b, csr_b, tei, tmpw, dis_t, cur_t, csr_t);

  // stage 1: bold GCN
  k_gemm_mfma<<<kN / 32, 256, 0, stream>>>(xb, pkb, hb);
  k_agg_ln<0><<<kN / 4, 256, 0, stream>>>(hb, x, nullptr, csr_b, base_b, dis_b,
                                          bb, gs, bs, nullptr, nullptr, sb);
  // stage 2: temporal GCN + final LN
  k_gemm_mfma<<<kN / 32, 256, 0, stream>>>(sb, pkt, hb);
  k_agg_ln<1><<<kN / 4, 256, 0, stream>>>(hb, sb, x, csr_t, base_t, dis_t,
                                          bt, gt, btn, gs, bs, outp);
}

// Round 7
// 311.929 us; speedup vs baseline: 1.0834x; 1.0165x over previous
//
#include <hip/hip_runtime.h>

constexpr int kN  = 16384;
constexpr int kEB = 524288;
constexpr int kET = 262144;
constexpr int kTA = 107;
constexpr float kEps = 1e-5f;
#define HN 256

typedef __attribute__((ext_vector_type(8))) short short8;
typedef __attribute__((ext_vector_type(4))) float floatx4;
typedef unsigned short u16;
typedef unsigned int u32;

#define GLOAD_LDS16(gp, lp)                                                    \
  __builtin_amdgcn_global_load_lds(                                            \
      (const __attribute__((address_space(1))) u32*)(gp),                      \
      (__attribute__((address_space(3))) u32*)(lp), 16, 0, 0)

__device__ __forceinline__ float wsum(float v) {
#pragma unroll
  for (int m = 1; m < 64; m <<= 1) v += __shfl_xor(v, m, 64);
  return v;
}

__device__ __forceinline__ u32 bf16rn(float f) {
  u32 u = __float_as_uint(f);
  return (u + 0x7FFFu + ((u >> 16) & 1u)) >> 16;
}
__device__ __forceinline__ u32 pack2(float a, float b) {
  return bf16rn(a) | (bf16rn(b) << 16);
}
__device__ __forceinline__ float bf2f(u16 v) {
  return __uint_as_float(((u32)v) << 16);
}
__device__ __forceinline__ u32 cvtpk(float lo, float hi) {
  u32 r;
  asm("v_cvt_pk_bf16_f32 %0, %1, %2" : "=v"(r) : "v"(lo), "v"(hi));
  return r;
}
// XOR swizzle for 512B-row tiles (bits 9-11 -> 4-6)
__device__ __forceinline__ u32 swz512(u32 b) { return b ^ (((b >> 9) & 7u) << 4); }

// ---- pack w1/Wb/Wt into MFMA-fragment-ordered bf16 + proj param table ----
// layout: [ktile][colTile(16)][lane(64)][e(8)];  k = ktile*32 + (lane>>4)*8 + e,
// col = colTile*16 + (lane&15)
__global__ __launch_bounds__(256)
void k_pack(const float* __restrict__ w1, const float* __restrict__ Wb,
            const float* __restrict__ Wt, const float* __restrict__ b1,
            const float* __restrict__ pg, const float* __restrict__ pbeta,
            const float* __restrict__ w2, u16* __restrict__ pk1,
            u16* __restrict__ pkb, u16* __restrict__ pkt,
            float4* __restrict__ pp) {
  int idx = blockIdx.x * 256 + threadIdx.x;
  if (idx < 32768) {                       // w1: K=128 padded from 107
    int e = idx & 7, lane = (idx >> 3) & 63, ct = (idx >> 9) & 15, kk = idx >> 13;
    int k = kk * 32 + (lane >> 4) * 8 + e, col = ct * 16 + (lane & 15);
    pk1[idx] = (u16)(k < kTA ? bf16rn(w1[(size_t)k * 256 + col]) : 0);
  } else if (idx < 163840) {
    int j = idx - 32768;
    const float* W = (j < 65536) ? Wb : Wt;
    u16* pk = (j < 65536) ? pkb : pkt;
    int t = j & 65535;
    int e = t & 7, lane = (t >> 3) & 63, ct = (t >> 9) & 15, kt = t >> 13;
    int k = kt * 32 + (lane >> 4) * 8 + e, col = ct * 16 + (lane & 15);
    pk[t] = (u16)bf16rn(W[(size_t)k * 256 + col]);
  } else if (idx < 163840 + 256) {
    int col = idx - 163840;
    pp[col] = make_float4(b1[col], pg[col], pbeta[col], w2[col]);
  }
}

// ---- fp32 -> bf16 convert (x -> xb), 8 elements/thread ----
__global__ __launch_bounds__(256)
void k_cvt(const float* __restrict__ in, u16* __restrict__ out) {
  size_t i = (size_t)(blockIdx.x * 256 + threadIdx.x) * 8;
  float4 a = *(const float4*)(in + i);
  float4 b = *(const float4*)(in + i + 4);
  uint4 o = make_uint4(pack2(a.x, a.y), pack2(a.z, a.w),
                       pack2(b.x, b.y), pack2(b.z, b.w));
  *(uint4*)(out + i) = o;
}

// ---- fused edge prep for both graphs: degree + count ----
__global__ __launch_bounds__(256)
void k_edge_prep_both(const int* __restrict__ bcol, const float* __restrict__ bw,
                      const int* __restrict__ tcol, const float* __restrict__ tw,
                      float* __restrict__ deg_b, int* __restrict__ cnt_b,
                      float* __restrict__ deg_t, int* __restrict__ cnt_t) {
  int e = blockIdx.x * 256 + threadIdx.x;
  if (e < kEB) {
    int c = bcol[e];
    atomicAdd(&deg_b[c], bw[e]);
    atomicAdd(&cnt_b[c], 1);
  } else {
    int t = e - kEB;
    int c = tcol[t];
    atomicAdd(&deg_t[c], tw[t]);
    atomicAdd(&cnt_t[c], 1);
  }
}

// ---- exclusive scan (one block per graph) ----
__global__ __launch_bounds__(256)
void k_scan_both(const int* __restrict__ cnt_b, int* __restrict__ base_b,
                 int* __restrict__ cur_b, const int* __restrict__ cnt_t,
                 int* __restrict__ base_t, int* __restrict__ cur_t) {
  const int* cnt = blockIdx.x ? cnt_t : cnt_b;
  int* base = blockIdx.x ? base_t : base_b;
  int* cur  = blockIdx.x ? cur_t : cur_b;
  __shared__ int part[256];
  int tid = threadIdx.x;
  int per = kN >> 8;
  int i0 = tid * per;
  int s = 0;
  for (int k = 0; k < per; ++k) s += cnt[i0 + k];
  part[tid] = s;
  __syncthreads();
  for (int off = 1; off < 256; off <<= 1) {
    int v = (tid >= off) ? part[tid - off] : 0;
    __syncthreads();
    part[tid] += v;
    __syncthreads();
  }
  int run = (tid == 0) ? 0 : part[tid - 1];
  for (int k = 0; k < per; ++k) {
    base[i0 + k] = run; cur[i0 + k] = run; run += cnt[i0 + k];
  }
  if (tid == 255) base[kN] = run;
}

__global__ __launch_bounds__(256)
void k_dis_both(const float* __restrict__ deg_b, float* __restrict__ dis_b,
                const float* __restrict__ deg_t, float* __restrict__ dis_t) {
  int i = blockIdx.x * 256 + threadIdx.x;
  if (i < kN) {
    float d = deg_b[i] + 1.0f;
    dis_b[i] = (d > 0.f) ? rsqrtf(d) : 0.f;
  } else {
    int t = i - kN;
    float d = deg_t[t] + 1.0f;
    dis_t[t] = (d > 0.f) ? rsqrtf(d) : 0.f;
  }
}

// ---- CSR fill for both graphs: per edge store (src, norm) packed ----
__global__ __launch_bounds__(256)
void k_fill_both(const int* __restrict__ bei, const float* __restrict__ bw,
                 const float* __restrict__ dis_b, int* __restrict__ cur_b,
                 int2* __restrict__ csr_b, const int* __restrict__ tei,
                 const float* __restrict__ tw, const float* __restrict__ dis_t,
                 int* __restrict__ cur_t, int2* __restrict__ csr_t) {
  int e = blockIdx.x * 256 + threadIdx.x;
  if (e < kEB) {
    int r = bei[e], c = bei[kEB + e];
    float nrm = dis_b[r] * bw[e] * dis_b[c];
    int pos = atomicAdd(&cur_b[c], 1);
    csr_b[pos] = make_int2(r, __float_as_int(nrm));
  } else {
    int t = e - kEB;
    int r = tei[t], c = tei[kET + t];
    float nrm = dis_t[r] * tw[t] * dis_t[c];
    int pos = atomicAdd(&cur_t[c], 1);
    csr_t[pos] = make_int2(r, __float_as_int(nrm));
  }
}

// ---- bf16-MFMA GEMM: Cb[M,256] = Ab[M,256] @ W, all bf16 (fp32 accum) ----
// 32 rows/block, 4 waves x 64 cols, packed W fragments, A via global_load_lds.
__global__ __launch_bounds__(256)
void k_gemm_mfma(const u16* __restrict__ Ab, const u16* __restrict__ pkW,
                 u16* __restrict__ Cb) {
  __shared__ __align__(16) u16 Atile[32 * 256];   // 16 KB, swizzled (512B rows)
  int tid = threadIdx.x;
  int w = tid >> 6, lane = tid & 63, low4 = lane & 15, hi = lane >> 4;
  int row0 = blockIdx.x * 32;

  const char* asrc = (const char*)(Ab + (size_t)row0 * 256);
#pragma unroll
  for (int i = 0; i < 4; ++i) {
    u32 d = (u32)(((i * 4 + w) * 64 + lane) * 16);
    GLOAD_LDS16(asrc + swz512(d), (char*)Atile + (i * 4 + w) * 1024);
  }

  floatx4 acc[2][4];
#pragma unroll
  for (int rt = 0; rt < 2; ++rt)
#pragma unroll
    for (int nn = 0; nn < 4; ++nn) acc[rt][nn] = (floatx4){0.f, 0.f, 0.f, 0.f};

  __syncthreads();   // drains vmcnt -> A tile ready

#pragma unroll
  for (int kt = 0; kt < 8; ++kt) {
    short8 bfr[4];
    const u16* pw = pkW + ((size_t)(kt * 16 + w * 4) * 64 + lane) * 8;
#pragma unroll
    for (int nn = 0; nn < 4; ++nn) bfr[nn] = *(const short8*)(pw + nn * 512);
    short8 afr[2];
#pragma unroll
    for (int rt = 0; rt < 2; ++rt) {
      u32 p = (u32)((rt * 16 + low4) * 512 + (kt * 32 + hi * 8) * 2);
      afr[rt] = *(const short8*)((const char*)Atile + swz512(p));
    }
#pragma unroll
    for (int rt = 0; rt < 2; ++rt)
#pragma unroll
      for (int nn = 0; nn < 4; ++nn)
        acc[rt][nn] = __builtin_amdgcn_mfma_f32_16x16x32_bf16(afr[rt], bfr[nn],
                                                              acc[rt][nn], 0, 0, 0);
  }
#pragma unroll
  for (int rt = 0; rt < 2; ++rt)
#pragma unroll
    for (int nn = 0; nn < 4; ++nn)
#pragma unroll
      for (int j = 0; j < 4; ++j) {
        int row = row0 + rt * 16 + hi * 4 + j;
        int col = w * 64 + nn * 16 + low4;
        Cb[(size_t)row * 256 + col] = (u16)bf16rn(acc[rt][nn][j]);
      }
}

// ---- temporal edge MLP via MFMA, no LDS, no barriers ----
// Wave w owns edges [blk*64 + w*16, +16) x all 256 cols. A-fragments loaded
// directly from global; nn-outer loop keeps one acc live; hv packed to bf16.
// NO waves-per-EU cap: the ~90-reg live set must stay in registers (r6's
// launch_bounds(256,4) cap spilled hvpk -> 200 MB of scratch HBM traffic).
__global__ __launch_bounds__(256)
void k_proj_mfma(const float* __restrict__ attr, const u16* __restrict__ pk1,
                 const float* __restrict__ b1, const float4* __restrict__ pp,
                 const float* __restrict__ b2, float* __restrict__ temp_w) {
  int tid = threadIdx.x;
  int w = tid >> 6, lane = tid & 63, low4 = lane & 15, hi = lane >> 4;
  int e0 = blockIdx.x * 64 + w * 16;
  const float* rowp = attr + (size_t)(e0 + low4) * kTA;

  // A fragments: row = low4, k = kk*32 + hi*8 + e (zero-pad k >= 107)
  short8 a[4];
#pragma unroll
  for (int kk = 0; kk < 4; ++kk) {
    int kb = kk * 32 + hi * 8;
    float v[8];
#pragma unroll
    for (int e = 0; e < 8; ++e)
      v[e] = (kk < 3 || kb + e < kTA) ? rowp[kb + e] : 0.f;
    union { short8 s8; uint4 u4; } fr;
    fr.u4 = make_uint4(cvtpk(v[0], v[1]), cvtpk(v[2], v[3]),
                       cvtpk(v[4], v[5]), cvtpk(v[6], v[7]));
    a[kk] = fr.s8;
  }

  u32 hvpk[16][2];
  float s1[4] = {0.f, 0.f, 0.f, 0.f}, s2[4] = {0.f, 0.f, 0.f, 0.f};
#pragma unroll
  for (int nn = 0; nn < 16; ++nn) {
    floatx4 acc = (floatx4){0.f, 0.f, 0.f, 0.f};
#pragma unroll
    for (int kk = 0; kk < 4; ++kk) {
      short8 bfr = *(const short8*)(pk1 + ((size_t)(kk * 16 + nn) * 64 + lane) * 8);
      acc = __builtin_amdgcn_mfma_f32_16x16x32_bf16(a[kk], bfr, acc, 0, 0, 0);
    }
    float b1v = b1[nn * 16 + low4];
    float h0 = acc[0] + b1v, h1 = acc[1] + b1v, h2 = acc[2] + b1v, h3 = acc[3] + b1v;
    s1[0] += h0; s2[0] += h0 * h0;
    s1[1] += h1; s2[1] += h1 * h1;
    s1[2] += h2; s2[2] += h2 * h2;
    s1[3] += h3; s2[3] += h3 * h3;
    hvpk[nn][0] = cvtpk(h0, h1);
    hvpk[nn][1] = cvtpk(h2, h3);
  }

  // per-row LN stats: reduce over the 16 low4 lanes
  float mean[4], inv[4];
#pragma unroll
  for (int j = 0; j < 4; ++j) {
#pragma unroll
    for (int m = 1; m < 16; m <<= 1) {
      s1[j] += __shfl_xor(s1[j], m, 64);
      s2[j] += __shfl_xor(s2[j], m, 64);
    }
    mean[j] = s1[j] * (1.f / 256);
    inv[j] = rsqrtf(s2[j] * (1.f / 256) - mean[j] * mean[j] + kEps);
  }

  // y = relu(LN(hv)); d_j = sum_cols y * w2
  float d[4] = {0.f, 0.f, 0.f, 0.f};
#pragma unroll
  for (int nn = 0; nn < 16; ++nn) {
    float4 p = pp[nn * 16 + low4];   // (b1, g, beta, w2)
    float h0 = bf2f((u16)(hvpk[nn][0] & 0xFFFF));
    float h1 = bf2f((u16)(hvpk[nn][0] >> 16));
    float h2 = bf2f((u16)(hvpk[nn][1] & 0xFFFF));
    float h3 = bf2f((u16)(hvpk[nn][1] >> 16));
    d[0] += fmaxf((h0 - mean[0]) * inv[0] * p.y + p.z, 0.f) * p.w;
    d[1] += fmaxf((h1 - mean[1]) * inv[1] * p.y + p.z, 0.f) * p.w;
    d[2] += fmaxf((h2 - mean[2]) * inv[2] * p.y + p.z, 0.f) * p.w;
    d[3] += fmaxf((h3 - mean[3]) * inv[3] * p.y + p.z, 0.f) * p.w;
  }
  float b2s = b2[0];
#pragma unroll
  for (int j = 0; j < 4; ++j) {
#pragma unroll
    for (int m = 1; m < 16; m <<= 1) d[j] += __shfl_xor(d[j], m, 64);
    if (low4 == 0) temp_w[e0 + hi * 4 + j] = d[j] + b2s;
  }
}

// ---- fused gather-aggregate (bf16 h) + bias + residual + LN + relu ----
// FINAL=0: resid fp32 (x), out bf16 (sb). FINAL=1: resid bf16 (sb), out fp32.
template <int FINAL>
__global__ __launch_bounds__(256)
void k_agg_ln(const u16* __restrict__ h, const void* __restrict__ residv,
              const float* __restrict__ x0, const int2* __restrict__ csr,
              const int* __restrict__ basep, const float* __restrict__ dis,
              const float* __restrict__ bias, const float* __restrict__ g1,
              const float* __restrict__ b1, const float* __restrict__ g2,
              const float* __restrict__ b2, void* __restrict__ outv) {
  int wave = threadIdx.x >> 6, lane = threadIdx.x & 63;
  int node = (blockIdx.x << 2) + wave;
  int c = lane << 2;
  float di = dis[node];
  ushort4 hs = *(const ushort4*)(h + (size_t)node * HN + c);
  float sl = di * di;
  float4 acc = make_float4(bf2f(hs.x) * sl, bf2f(hs.y) * sl,
                           bf2f(hs.z) * sl, bf2f(hs.w) * sl);
  int e0 = basep[node], e1 = basep[node + 1];
  if (e0 < e1) {
    int2 p = csr[e0];
    for (int k = e0; k < e1; ++k) {
      int2 pn = p;
      if (k + 1 < e1) pn = csr[k + 1];
      float nrm = __int_as_float(p.y);
      ushort4 hv = *(const ushort4*)(h + (size_t)p.x * HN + c);
      acc.x += nrm * bf2f(hv.x); acc.y += nrm * bf2f(hv.y);
      acc.z += nrm * bf2f(hv.z); acc.w += nrm * bf2f(hv.w);
      p = pn;
    }
  }
  float4 bb = *(const float4*)(bias + c);
  float4 rr;
  if (!FINAL) {
    rr = *(const float4*)((const float*)residv + (size_t)node * HN + c);
  } else {
    ushort4 rv = *(const ushort4*)((const u16*)residv + (size_t)node * HN + c);
    rr = make_float4(bf2f(rv.x), bf2f(rv.y), bf2f(rv.z), bf2f(rv.w));
  }
  float v0 = acc.x + bb.x + rr.x;
  float v1 = acc.y + bb.y + rr.y;
  float v2 = acc.z + bb.z + rr.z;
  float v3 = acc.w + bb.w + rr.w;
  float sum = wsum(v0 + v1 + v2 + v3);
  float ss  = wsum(v0 * v0 + v1 * v1 + v2 * v2 + v3 * v3);
  float mean = sum * (1.f / HN);
  float inv = rsqrtf(ss * (1.f / HN) - mean * mean + kEps);
  float4 g = *(const float4*)(g1 + c);
  float4 b = *(const float4*)(b1 + c);
  float y0 = fmaxf((v0 - mean) * inv * g.x + b.x, 0.f);
  float y1 = fmaxf((v1 - mean) * inv * g.y + b.y, 0.f);
  float y2 = fmaxf((v2 - mean) * inv * g.z + b.z, 0.f);
  float y3 = fmaxf((v3 - mean) * inv * g.w + b.w, 0.f);
  if (!FINAL) {
    uint2 o = make_uint2(pack2(y0, y1), pack2(y2, y3));
    *(uint2*)((u16*)outv + (size_t)node * HN + c) = o;
  } else {
    float4 xx = *(const float4*)(x0 + (size_t)node * HN + c);
    float z0 = y0 + xx.x, z1 = y1 + xx.y, z2 = y2 + xx.z, z3 = y3 + xx.w;
    float s2 = wsum(z0 + z1 + z2 + z3);
    float q2 = wsum(z0 * z0 + z1 * z1 + z2 * z2 + z3 * z3);
    float m2 = s2 * (1.f / HN);
    float i2 = rsqrtf(q2 * (1.f / HN) - m2 * m2 + kEps);
    float4 G = *(const float4*)(g2 + c);
    float4 B = *(const float4*)(b2 + c);
    float4 o = make_float4((z0 - m2) * i2 * G.x + B.x, (z1 - m2) * i2 * G.y + B.y,
                           (z2 - m2) * i2 * G.z + B.z, (z3 - m2) * i2 * G.w + B.w);
    *(float4*)((float*)outv + (size_t)node * HN + c) = o;
  }
}

extern "C" void kernel_launch(void* const* d_in, const int* in_sizes, int n_in,
                              void* d_out, int out_size, void* d_ws, size_t ws_size,
                              hipStream_t stream) {
  const float* x     = (const float*)d_in[0];
  const int*   bei   = (const int*)d_in[1];
  const float* bew   = (const float*)d_in[2];
  const int*   tei   = (const int*)d_in[3];
  const float* tattr = (const float*)d_in[4];
  const float* Wb    = (const float*)d_in[5];
  const float* bb    = (const float*)d_in[6];
  const float* Wt    = (const float*)d_in[7];
  const float* bt    = (const float*)d_in[8];
  const float* gs    = (const float*)d_in[9];
  const float* bs    = (const float*)d_in[10];
  const float* gt    = (const float*)d_in[11];
  const float* btn   = (const float*)d_in[12];
  const float* pw1   = (const float*)d_in[13];
  const float* pb1   = (const float*)d_in[14];
  const float* pg    = (const float*)d_in[15];
  const float* pbeta = (const float*)d_in[16];
  const float* pw2   = (const float*)d_in[17];
  const float* pb2   = (const float*)d_in[18];
  float* outp = (float*)d_out;

  size_t off = 0;
  auto alloc = [&](size_t bytes) -> void* {
    void* p = (char*)d_ws + off;
    off += (bytes + 255) & ~(size_t)255;
    return p;
  };
  float* deg_b = (float*)alloc(kN * 4);
  float* deg_t = (float*)alloc(kN * 4);
  int*   cnt_b = (int*)alloc(kN * 4);
  int*   cnt_t = (int*)alloc(kN * 4);       // deg_b..cnt_t contiguous: one memset
  float* dis_b = (float*)alloc(kN * 4);
  float* dis_t = (float*)alloc(kN * 4);
  int*   base_b = (int*)alloc((kN + 1) * 4);
  int*   base_t = (int*)alloc((kN + 1) * 4);
  int*   cur_b  = (int*)alloc(kN * 4);
  int*   cur_t  = (int*)alloc(kN * 4);
  float* tmpw   = (float*)alloc(kET * 4);
  int2*  csr_b  = (int2*)alloc((size_t)kEB * 8);
  int2*  csr_t  = (int2*)alloc((size_t)kET * 8);
  u16*   pk1 = (u16*)alloc(32768 * 2);
  u16*   pkb = (u16*)alloc(65536 * 2);
  u16*   pkt = (u16*)alloc(65536 * 2);
  float4* pp = (float4*)alloc(256 * 16);
  u16*   xb  = (u16*)alloc((size_t)kN * HN * 2);
  u16*   hb  = (u16*)alloc((size_t)kN * HN * 2);
  u16*   sb  = (u16*)alloc((size_t)kN * HN * 2);
  (void)ws_size; (void)in_sizes; (void)n_in; (void)out_size;

  hipMemsetAsync(deg_b, 0, (size_t)4 * kN * 4, stream);

  // const prep
  k_pack<<<641, 256, 0, stream>>>(pw1, Wb, Wt, pb1, pg, pbeta, pw2,
                                  pk1, pkb, pkt, pp);
  k_cvt<<<kN * HN / 8 / 256, 256, 0, stream>>>(x, xb);

  // temporal edge weights (independent of node pipeline)
  k_proj_mfma<<<kET / 64, 256, 0, stream>>>(tattr, pk1, pb1, pp, pb2, tmpw);

  // graph structure for both graphs
  k_edge_prep_both<<<(kEB + kET) / 256, 256, 0, stream>>>(
      bei + kEB, bew, tei + kET, tmpw, deg_b, cnt_b, deg_t, cnt_t);
  k_scan_both<<<2, 256, 0, stream>>>(cnt_b, base_b, cur_b, cnt_t, base_t, cur_t);
  k_dis_both<<<2 * kN / 256, 256, 0, stream>>>(deg_b, dis_b, deg_t, dis_t);
  k_fill_both<<<(kEB + kET) / 256, 256, 0, stream>>>(
      bei, bew, dis_b, cur_b, csr_b, tei, tmpw, dis_t, cur_t, csr_t);

  // stage 1: bold GCN
  k_gemm_mfma<<<kN / 32, 256, 0, stream>>>(xb, pkb, hb);
  k_agg_ln<0><<<kN / 4, 256, 0, stream>>>(hb, x, nullptr, csr_b, base_b, dis_b,
                                          bb, gs, bs, nullptr, nullptr, sb);
  // stage 2: temporal GCN + final LN
  k_gemm_mfma<<<kN / 32, 256, 0, stream>>>(sb, pkt, hb);
  k_agg_ln<1><<<kN / 4, 256, 0, stream>>>(hb, sb, x, csr_t, base_t, dis_t,
                                          bt, gt, btn, gs, bs, outp);
}

// Round 8
// 281.966 us; speedup vs baseline: 1.1986x; 1.1063x over previous
//
#include <hip/hip_runtime.h>

constexpr int kN  = 16384;
constexpr int kEB = 524288;
constexpr int kET = 262144;
constexpr int kTA = 107;
constexpr float kEps = 1e-5f;
#define HN 256

typedef __attribute__((ext_vector_type(8))) short short8;
typedef __attribute__((ext_vector_type(4))) float floatx4;
typedef unsigned short u16;
typedef unsigned int u32;

#define GLOAD_LDS16(gp, lp)                                                    \
  __builtin_amdgcn_global_load_lds(                                            \
      (const __attribute__((address_space(1))) u32*)(gp),                      \
      (__attribute__((address_space(3))) u32*)(lp), 16, 0, 0)

__device__ __forceinline__ float wsum(float v) {
#pragma unroll
  for (int m = 1; m < 64; m <<= 1) v += __shfl_xor(v, m, 64);
  return v;
}

__device__ __forceinline__ u32 bf16rn(float f) {
  u32 u = __float_as_uint(f);
  return (u + 0x7FFFu + ((u >> 16) & 1u)) >> 16;
}
__device__ __forceinline__ u32 pack2(float a, float b) {
  return bf16rn(a) | (bf16rn(b) << 16);
}
__device__ __forceinline__ float bf2f(u16 v) {
  return __uint_as_float(((u32)v) << 16);
}
__device__ __forceinline__ u32 cvtpk(float lo, float hi) {
  u32 r;
  asm("v_cvt_pk_bf16_f32 %0, %1, %2" : "=v"(r) : "v"(lo), "v"(hi));
  return r;
}
// XOR swizzle for 512B-row tiles (bits 9-11 -> 4-6)
__device__ __forceinline__ u32 swz512(u32 b) { return b ^ (((b >> 9) & 7u) << 4); }

// ---- pack w1/Wb/Wt into MFMA-fragment-ordered bf16 + proj param table ----
// layout: [ktile][colTile(16)][lane(64)][e(8)];  k = ktile*32 + (lane>>4)*8 + e,
// col = colTile*16 + (lane&15)
__global__ __launch_bounds__(256)
void k_pack(const float* __restrict__ w1, const float* __restrict__ Wb,
            const float* __restrict__ Wt, const float* __restrict__ b1,
            const float* __restrict__ pg, const float* __restrict__ pbeta,
            const float* __restrict__ w2, u16* __restrict__ pk1,
            u16* __restrict__ pkb, u16* __restrict__ pkt,
            float4* __restrict__ pp) {
  int idx = blockIdx.x * 256 + threadIdx.x;
  if (idx < 32768) {                       // w1: K=128 padded from 107
    int e = idx & 7, lane = (idx >> 3) & 63, ct = (idx >> 9) & 15, kk = idx >> 13;
    int k = kk * 32 + (lane >> 4) * 8 + e, col = ct * 16 + (lane & 15);
    pk1[idx] = (u16)(k < kTA ? bf16rn(w1[(size_t)k * 256 + col]) : 0);
  } else if (idx < 163840) {
    int j = idx - 32768;
    const float* W = (j < 65536) ? Wb : Wt;
    u16* pk = (j < 65536) ? pkb : pkt;
    int t = j & 65535;
    int e = t & 7, lane = (t >> 3) & 63, ct = (t >> 9) & 15, kt = t >> 13;
    int k = kt * 32 + (lane >> 4) * 8 + e, col = ct * 16 + (lane & 15);
    pk[t] = (u16)bf16rn(W[(size_t)k * 256 + col]);
  } else if (idx < 163840 + 256) {
    int col = idx - 163840;
    pp[col] = make_float4(b1[col], pg[col], pbeta[col], w2[col]);
  }
}

// ---- fp32 -> bf16 convert (x -> xb), 8 elements/thread ----
__global__ __launch_bounds__(256)
void k_cvt(const float* __restrict__ in, u16* __restrict__ out) {
  size_t i = (size_t)(blockIdx.x * 256 + threadIdx.x) * 8;
  float4 a = *(const float4*)(in + i);
  float4 b = *(const float4*)(in + i + 4);
  uint4 o = make_uint4(pack2(a.x, a.y), pack2(a.z, a.w),
                       pack2(b.x, b.y), pack2(b.z, b.w));
  *(uint4*)(out + i) = o;
}

// ---- fused edge prep for both graphs: degree + count ----
__global__ __launch_bounds__(256)
void k_edge_prep_both(const int* __restrict__ bcol, const float* __restrict__ bw,
                      const int* __restrict__ tcol, const float* __restrict__ tw,
                      float* __restrict__ deg_b, int* __restrict__ cnt_b,
                      float* __restrict__ deg_t, int* __restrict__ cnt_t) {
  int e = blockIdx.x * 256 + threadIdx.x;
  if (e < kEB) {
    int c = bcol[e];
    atomicAdd(&deg_b[c], bw[e]);
    atomicAdd(&cnt_b[c], 1);
  } else {
    int t = e - kEB;
    int c = tcol[t];
    atomicAdd(&deg_t[c], tw[t]);
    atomicAdd(&cnt_t[c], 1);
  }
}

// ---- exclusive scan (one block per graph) ----
__global__ __launch_bounds__(256)
void k_scan_both(const int* __restrict__ cnt_b, int* __restrict__ base_b,
                 int* __restrict__ cur_b, const int* __restrict__ cnt_t,
                 int* __restrict__ base_t, int* __restrict__ cur_t) {
  const int* cnt = blockIdx.x ? cnt_t : cnt_b;
  int* base = blockIdx.x ? base_t : base_b;
  int* cur  = blockIdx.x ? cur_t : cur_b;
  __shared__ int part[256];
  int tid = threadIdx.x;
  int per = kN >> 8;
  int i0 = tid * per;
  int s = 0;
  for (int k = 0; k < per; ++k) s += cnt[i0 + k];
  part[tid] = s;
  __syncthreads();
  for (int off = 1; off < 256; off <<= 1) {
    int v = (tid >= off) ? part[tid - off] : 0;
    __syncthreads();
    part[tid] += v;
    __syncthreads();
  }
  int run = (tid == 0) ? 0 : part[tid - 1];
  for (int k = 0; k < per; ++k) {
    base[i0 + k] = run; cur[i0 + k] = run; run += cnt[i0 + k];
  }
  if (tid == 255) base[kN] = run;
}

__global__ __launch_bounds__(256)
void k_dis_both(const float* __restrict__ deg_b, float* __restrict__ dis_b,
                const float* __restrict__ deg_t, float* __restrict__ dis_t) {
  int i = blockIdx.x * 256 + threadIdx.x;
  if (i < kN) {
    float d = deg_b[i] + 1.0f;
    dis_b[i] = (d > 0.f) ? rsqrtf(d) : 0.f;
  } else {
    int t = i - kN;
    float d = deg_t[t] + 1.0f;
    dis_t[t] = (d > 0.f) ? rsqrtf(d) : 0.f;
  }
}

// ---- CSR fill for both graphs: per edge store (src, norm) packed ----
__global__ __launch_bounds__(256)
void k_fill_both(const int* __restrict__ bei, const float* __restrict__ bw,
                 const float* __restrict__ dis_b, int* __restrict__ cur_b,
                 int2* __restrict__ csr_b, const int* __restrict__ tei,
                 const float* __restrict__ tw, const float* __restrict__ dis_t,
                 int* __restrict__ cur_t, int2* __restrict__ csr_t) {
  int e = blockIdx.x * 256 + threadIdx.x;
  if (e < kEB) {
    int r = bei[e], c = bei[kEB + e];
    float nrm = dis_b[r] * bw[e] * dis_b[c];
    int pos = atomicAdd(&cur_b[c], 1);
    csr_b[pos] = make_int2(r, __float_as_int(nrm));
  } else {
    int t = e - kEB;
    int r = tei[t], c = tei[kET + t];
    float nrm = dis_t[r] * tw[t] * dis_t[c];
    int pos = atomicAdd(&cur_t[c], 1);
    csr_t[pos] = make_int2(r, __float_as_int(nrm));
  }
}

// ---- bf16-MFMA GEMM: Cb[M,256] = Ab[M,256] @ W, all bf16 (fp32 accum) ----
// 32 rows/block, 4 waves x 64 cols, packed W fragments, A via global_load_lds.
__global__ __launch_bounds__(256)
void k_gemm_mfma(const u16* __restrict__ Ab, const u16* __restrict__ pkW,
                 u16* __restrict__ Cb) {
  __shared__ __align__(16) u16 Atile[32 * 256];   // 16 KB, swizzled (512B rows)
  int tid = threadIdx.x;
  int w = tid >> 6, lane = tid & 63, low4 = lane & 15, hi = lane >> 4;
  int row0 = blockIdx.x * 32;

  const char* asrc = (const char*)(Ab + (size_t)row0 * 256);
#pragma unroll
  for (int i = 0; i < 4; ++i) {
    u32 d = (u32)(((i * 4 + w) * 64 + lane) * 16);
    GLOAD_LDS16(asrc + swz512(d), (char*)Atile + (i * 4 + w) * 1024);
  }

  floatx4 acc[2][4];
#pragma unroll
  for (int rt = 0; rt < 2; ++rt)
#pragma unroll
    for (int nn = 0; nn < 4; ++nn) acc[rt][nn] = (floatx4){0.f, 0.f, 0.f, 0.f};

  __syncthreads();   // drains vmcnt -> A tile ready

#pragma unroll
  for (int kt = 0; kt < 8; ++kt) {
    short8 bfr[4];
    const u16* pw = pkW + ((size_t)(kt * 16 + w * 4) * 64 + lane) * 8;
#pragma unroll
    for (int nn = 0; nn < 4; ++nn) bfr[nn] = *(const short8*)(pw + nn * 512);
    short8 afr[2];
#pragma unroll
    for (int rt = 0; rt < 2; ++rt) {
      u32 p = (u32)((rt * 16 + low4) * 512 + (kt * 32 + hi * 8) * 2);
      afr[rt] = *(const short8*)((const char*)Atile + swz512(p));
    }
#pragma unroll
    for (int rt = 0; rt < 2; ++rt)
#pragma unroll
      for (int nn = 0; nn < 4; ++nn)
        acc[rt][nn] = __builtin_amdgcn_mfma_f32_16x16x32_bf16(afr[rt], bfr[nn],
                                                              acc[rt][nn], 0, 0, 0);
  }
#pragma unroll
  for (int rt = 0; rt < 2; ++rt)
#pragma unroll
    for (int nn = 0; nn < 4; ++nn)
#pragma unroll
      for (int j = 0; j < 4; ++j) {
        int row = row0 + rt * 16 + hi * 4 + j;
        int col = w * 64 + nn * 16 + low4;
        Cb[(size_t)row * 256 + col] = (u16)bf16rn(acc[rt][nn][j]);
      }
}

// ---- temporal edge MLP via MFMA, B (pk1) staged once per block in LDS ----
// 512 threads = 8 waves, 128 edges/block; wave w owns 16 edges x 256 cols.
// B reads become conflict-free linear ds_read_b128 (lane i -> bytes i*16);
// B L2 traffic drops 1 GB -> 256 MB. A-frags direct from global (no barrier
// after stage-consume; one syncthreads total).
__global__ __launch_bounds__(512)
void k_proj_mfma(const float* __restrict__ attr, const u16* __restrict__ pk1,
                 const float* __restrict__ b1, const float4* __restrict__ pp,
                 const float* __restrict__ b2, float* __restrict__ temp_w) {
  __shared__ __align__(16) u16 Btile[32768];   // 64 KB = whole packed w1
  int tid = threadIdx.x;
  int w = tid >> 6, lane = tid & 63, low4 = lane & 15, hi = lane >> 4;
  int e0 = blockIdx.x * 128 + w * 16;
  const float* rowp = attr + (size_t)(e0 + low4) * kTA;

  // stage pk1: 8 iters x 512 threads x 16 B, linear (wave-uniform dest + lane*16)
#pragma unroll
  for (int it = 0; it < 8; ++it) {
    int chunk = it * 512 + tid;
    GLOAD_LDS16((const char*)pk1 + (size_t)chunk * 16,
                (char*)Btile + (it * 512 + w * 64) * 16);
  }

  // A fragments: row = low4, k = kk*32 + hi*8 + e (zero-pad k >= 107)
  short8 a[4];
#pragma unroll
  for (int kk = 0; kk < 4; ++kk) {
    int kb = kk * 32 + hi * 8;
    float v[8];
#pragma unroll
    for (int e = 0; e < 8; ++e)
      v[e] = (kk < 3 || kb + e < kTA) ? rowp[kb + e] : 0.f;
    union { short8 s8; uint4 u4; } fr;
    fr.u4 = make_uint4(cvtpk(v[0], v[1]), cvtpk(v[2], v[3]),
                       cvtpk(v[4], v[5]), cvtpk(v[6], v[7]));
    a[kk] = fr.s8;
  }

  __syncthreads();   // drains vmcnt -> Btile ready

  u32 hvpk[16][2];
  float s1[4] = {0.f, 0.f, 0.f, 0.f}, s2[4] = {0.f, 0.f, 0.f, 0.f};
#pragma unroll
  for (int nn = 0; nn < 16; ++nn) {
    floatx4 acc = (floatx4){0.f, 0.f, 0.f, 0.f};
#pragma unroll
    for (int kk = 0; kk < 4; ++kk) {
      short8 bfr = *(const short8*)(Btile + ((size_t)(kk * 16 + nn) * 64 + lane) * 8);
      acc = __builtin_amdgcn_mfma_f32_16x16x32_bf16(a[kk], bfr, acc, 0, 0, 0);
    }
    float b1v = b1[nn * 16 + low4];
    float h0 = acc[0] + b1v, h1 = acc[1] + b1v, h2 = acc[2] + b1v, h3 = acc[3] + b1v;
    s1[0] += h0; s2[0] += h0 * h0;
    s1[1] += h1; s2[1] += h1 * h1;
    s1[2] += h2; s2[2] += h2 * h2;
    s1[3] += h3; s2[3] += h3 * h3;
    hvpk[nn][0] = cvtpk(h0, h1);
    hvpk[nn][1] = cvtpk(h2, h3);
  }

  // per-row LN stats: reduce over the 16 low4 lanes
  float mean[4], inv[4];
#pragma unroll
  for (int j = 0; j < 4; ++j) {
#pragma unroll
    for (int m = 1; m < 16; m <<= 1) {
      s1[j] += __shfl_xor(s1[j], m, 64);
      s2[j] += __shfl_xor(s2[j], m, 64);
    }
    mean[j] = s1[j] * (1.f / 256);
    inv[j] = rsqrtf(s2[j] * (1.f / 256) - mean[j] * mean[j] + kEps);
  }

  // y = relu(LN(hv)); d_j = sum_cols y * w2
  float d[4] = {0.f, 0.f, 0.f, 0.f};
#pragma unroll
  for (int nn = 0; nn < 16; ++nn) {
    float4 p = pp[nn * 16 + low4];   // (b1, g, beta, w2)
    float h0 = bf2f((u16)(hvpk[nn][0] & 0xFFFF));
    float h1 = bf2f((u16)(hvpk[nn][0] >> 16));
    float h2 = bf2f((u16)(hvpk[nn][1] & 0xFFFF));
    float h3 = bf2f((u16)(hvpk[nn][1] >> 16));
    d[0] += fmaxf((h0 - mean[0]) * inv[0] * p.y + p.z, 0.f) * p.w;
    d[1] += fmaxf((h1 - mean[1]) * inv[1] * p.y + p.z, 0.f) * p.w;
    d[2] += fmaxf((h2 - mean[2]) * inv[2] * p.y + p.z, 0.f) * p.w;
    d[3] += fmaxf((h3 - mean[3]) * inv[3] * p.y + p.z, 0.f) * p.w;
  }
  float b2s = b2[0];
#pragma unroll
  for (int j = 0; j < 4; ++j) {
#pragma unroll
    for (int m = 1; m < 16; m <<= 1) d[j] += __shfl_xor(d[j], m, 64);
    if (low4 == 0) temp_w[e0 + hi * 4 + j] = d[j] + b2s;
  }
}

// ---- fused gather-aggregate (bf16 h) + bias + residual + LN + relu ----
// Edge loop unrolled x2: both neighbor-row loads issued before FMAs (2x MLP).
// FINAL=0: resid fp32 (x), out bf16 (sb). FINAL=1: resid bf16 (sb), out fp32.
template <int FINAL>
__global__ __launch_bounds__(256)
void k_agg_ln(const u16* __restrict__ h, const void* __restrict__ residv,
              const float* __restrict__ x0, const int2* __restrict__ csr,
              const int* __restrict__ basep, const float* __restrict__ dis,
              const float* __restrict__ bias, const float* __restrict__ g1,
              const float* __restrict__ b1, const float* __restrict__ g2,
              const float* __restrict__ b2, void* __restrict__ outv) {
  int wave = threadIdx.x >> 6, lane = threadIdx.x & 63;
  int node = (blockIdx.x << 2) + wave;
  int c = lane << 2;
  float di = dis[node];
  ushort4 hs = *(const ushort4*)(h + (size_t)node * HN + c);
  float sl = di * di;
  float4 acc = make_float4(bf2f(hs.x) * sl, bf2f(hs.y) * sl,
                           bf2f(hs.z) * sl, bf2f(hs.w) * sl);
  int e0 = basep[node], e1 = basep[node + 1];
  int k = e0;
  for (; k + 2 <= e1; k += 2) {
    int2 pa = csr[k];
    int2 pb = csr[k + 1];
    float na = __int_as_float(pa.y), nb = __int_as_float(pb.y);
    ushort4 ha = *(const ushort4*)(h + (size_t)pa.x * HN + c);
    ushort4 hbv = *(const ushort4*)(h + (size_t)pb.x * HN + c);
    acc.x += na * bf2f(ha.x) + nb * bf2f(hbv.x);
    acc.y += na * bf2f(ha.y) + nb * bf2f(hbv.y);
    acc.z += na * bf2f(ha.z) + nb * bf2f(hbv.z);
    acc.w += na * bf2f(ha.w) + nb * bf2f(hbv.w);
  }
  if (k < e1) {
    int2 p = csr[k];
    float nrm = __int_as_float(p.y);
    ushort4 hv = *(const ushort4*)(h + (size_t)p.x * HN + c);
    acc.x += nrm * bf2f(hv.x); acc.y += nrm * bf2f(hv.y);
    acc.z += nrm * bf2f(hv.z); acc.w += nrm * bf2f(hv.w);
  }
  float4 bb = *(const float4*)(bias + c);
  float4 rr;
  if (!FINAL) {
    rr = *(const float4*)((const float*)residv + (size_t)node * HN + c);
  } else {
    ushort4 rv = *(const ushort4*)((const u16*)residv + (size_t)node * HN + c);
    rr = make_float4(bf2f(rv.x), bf2f(rv.y), bf2f(rv.z), bf2f(rv.w));
  }
  float v0 = acc.x + bb.x + rr.x;
  float v1 = acc.y + bb.y + rr.y;
  float v2 = acc.z + bb.z + rr.z;
  float v3 = acc.w + bb.w + rr.w;
  float sum = wsum(v0 + v1 + v2 + v3);
  float ss  = wsum(v0 * v0 + v1 * v1 + v2 * v2 + v3 * v3);
  float mean = sum * (1.f / HN);
  float inv = rsqrtf(ss * (1.f / HN) - mean * mean + kEps);
  float4 g = *(const float4*)(g1 + c);
  float4 b = *(const float4*)(b1 + c);
  float y0 = fmaxf((v0 - mean) * inv * g.x + b.x, 0.f);
  float y1 = fmaxf((v1 - mean) * inv * g.y + b.y, 0.f);
  float y2 = fmaxf((v2 - mean) * inv * g.z + b.z, 0.f);
  float y3 = fmaxf((v3 - mean) * inv * g.w + b.w, 0.f);
  if (!FINAL) {
    uint2 o = make_uint2(pack2(y0, y1), pack2(y2, y3));
    *(uint2*)((u16*)outv + (size_t)node * HN + c) = o;
  } else {
    float4 xx = *(const float4*)(x0 + (size_t)node * HN + c);
    float z0 = y0 + xx.x, z1 = y1 + xx.y, z2 = y2 + xx.z, z3 = y3 + xx.w;
    float s2 = wsum(z0 + z1 + z2 + z3);
    float q2 = wsum(z0 * z0 + z1 * z1 + z2 * z2 + z3 * z3);
    float m2 = s2 * (1.f / HN);
    float i2 = rsqrtf(q2 * (1.f / HN) - m2 * m2 + kEps);
    float4 G = *(const float4*)(g2 + c);
    float4 B = *(const float4*)(b2 + c);
    float4 o = make_float4((z0 - m2) * i2 * G.x + B.x, (z1 - m2) * i2 * G.y + B.y,
                           (z2 - m2) * i2 * G.z + B.z, (z3 - m2) * i2 * G.w + B.w);
    *(float4*)((float*)outv + (size_t)node * HN + c) = o;
  }
}

extern "C" void kernel_launch(void* const* d_in, const int* in_sizes, int n_in,
                              void* d_out, int out_size, void* d_ws, size_t ws_size,
                              hipStream_t stream) {
  const float* x     = (const float*)d_in[0];
  const int*   bei   = (const int*)d_in[1];
  const float* bew   = (const float*)d_in[2];
  const int*   tei   = (const int*)d_in[3];
  const float* tattr = (const float*)d_in[4];
  const float* Wb    = (const float*)d_in[5];
  const float* bb    = (const float*)d_in[6];
  const float* Wt    = (const float*)d_in[7];
  const float* bt    = (const float*)d_in[8];
  const float* gs    = (const float*)d_in[9];
  const float* bs    = (const float*)d_in[10];
  const float* gt    = (const float*)d_in[11];
  const float* btn   = (const float*)d_in[12];
  const float* pw1   = (const float*)d_in[13];
  const float* pb1   = (const float*)d_in[14];
  const float* pg    = (const float*)d_in[15];
  const float* pbeta = (const float*)d_in[16];
  const float* pw2   = (const float*)d_in[17];
  const float* pb2   = (const float*)d_in[18];
  float* outp = (float*)d_out;

  size_t off = 0;
  auto alloc = [&](size_t bytes) -> void* {
    void* p = (char*)d_ws + off;
    off += (bytes + 255) & ~(size_t)255;
    return p;
  };
  float* deg_b = (float*)alloc(kN * 4);
  float* deg_t = (float*)alloc(kN * 4);
  int*   cnt_b = (int*)alloc(kN * 4);
  int*   cnt_t = (int*)alloc(kN * 4);       // deg_b..cnt_t contiguous: one memset
  float* dis_b = (float*)alloc(kN * 4);
  float* dis_t = (float*)alloc(kN * 4);
  int*   base_b = (int*)alloc((kN + 1) * 4);
  int*   base_t = (int*)alloc((kN + 1) * 4);
  int*   cur_b  = (int*)alloc(kN * 4);
  int*   cur_t  = (int*)alloc(kN * 4);
  float* tmpw   = (float*)alloc(kET * 4);
  int2*  csr_b  = (int2*)alloc((size_t)kEB * 8);
  int2*  csr_t  = (int2*)alloc((size_t)kET * 8);
  u16*   pk1 = (u16*)alloc(32768 * 2);
  u16*   pkb = (u16*)alloc(65536 * 2);
  u16*   pkt = (u16*)alloc(65536 * 2);
  float4* pp = (float4*)alloc(256 * 16);
  u16*   xb  = (u16*)alloc((size_t)kN * HN * 2);
  u16*   hb  = (u16*)alloc((size_t)kN * HN * 2);
  u16*   sb  = (u16*)alloc((size_t)kN * HN * 2);
  (void)ws_size; (void)in_sizes; (void)n_in; (void)out_size;

  hipMemsetAsync(deg_b, 0, (size_t)4 * kN * 4, stream);

  // const prep
  k_pack<<<641, 256, 0, stream>>>(pw1, Wb, Wt, pb1, pg, pbeta, pw2,
                                  pk1, pkb, pkt, pp);
  k_cvt<<<kN * HN / 8 / 256, 256, 0, stream>>>(x, xb);

  // temporal edge weights (independent of node pipeline)
  k_proj_mfma<<<kET / 128, 512, 0, stream>>>(tattr, pk1, pb1, pp, pb2, tmpw);

  // graph structure for both graphs
  k_edge_prep_both<<<(kEB + kET) / 256, 256, 0, stream>>>(
      bei + kEB, bew, tei + kET, tmpw, deg_b, cnt_b, deg_t, cnt_t);
  k_scan_both<<<2, 256, 0, stream>>>(cnt_b, base_b, cur_b, cnt_t, base_t, cur_t);
  k_dis_both<<<2 * kN / 256, 256, 0, stream>>>(deg_b, dis_b, deg_t, dis_t);
  k_fill_both<<<(kEB + kET) / 256, 256, 0, stream>>>(
      bei, bew, dis_b, cur_b, csr_b, tei, tmpw, dis_t, cur_t, csr_t);

  // stage 1: bold GCN
  k_gemm_mfma<<<kN / 32, 256, 0, stream>>>(xb, pkb, hb);
  k_agg_ln<0><<<kN / 4, 256, 0, stream>>>(hb, x, nullptr, csr_b, base_b, dis_b,
                                          bb, gs, bs, nullptr, nullptr, sb);
  // stage 2: temporal GCN + final LN
  k_gemm_mfma<<<kN / 32, 256, 0, stream>>>(sb, pkt, hb);
  k_agg_ln<1><<<kN / 4, 256, 0, stream>>>(hb, sb, x, csr_t, base_t, dis_t,
                                          bt, gt, btn, gs, bs, outp);
}

// Round 9
// 278.011 us; speedup vs baseline: 1.2156x; 1.0142x over previous
//
#include <hip/hip_runtime.h>

constexpr int kN  = 16384;
constexpr int kEB = 524288;
constexpr int kET = 262144;
constexpr int kTA = 107;
constexpr float kEps = 1e-5f;
#define HN 256

typedef __attribute__((ext_vector_type(8))) short short8;
typedef __attribute__((ext_vector_type(4))) float floatx4;
typedef unsigned short u16;
typedef unsigned int u32;

#define GLOAD_LDS16(gp, lp)                                                    \
  __builtin_amdgcn_global_load_lds(                                            \
      (const __attribute__((address_space(1))) u32*)(gp),                      \
      (__attribute__((address_space(3))) u32*)(lp), 16, 0, 0)

__device__ __forceinline__ float wsum(float v) {
#pragma unroll
  for (int m = 1; m < 64; m <<= 1) v += __shfl_xor(v, m, 64);
  return v;
}

__device__ __forceinline__ u32 bf16rn(float f) {
  u32 u = __float_as_uint(f);
  return (u + 0x7FFFu + ((u >> 16) & 1u)) >> 16;
}
__device__ __forceinline__ u32 pack2(float a, float b) {
  return bf16rn(a) | (bf16rn(b) << 16);
}
__device__ __forceinline__ float bf2f(u16 v) {
  return __uint_as_float(((u32)v) << 16);
}
__device__ __forceinline__ u32 cvtpk(float lo, float hi) {
  u32 r;
  asm("v_cvt_pk_bf16_f32 %0, %1, %2" : "=v"(r) : "v"(lo), "v"(hi));
  return r;
}
// XOR swizzle for 512B-row tiles (bits 9-11 -> 4-6)
__device__ __forceinline__ u32 swz512(u32 b) { return b ^ (((b >> 9) & 7u) << 4); }

// ---- pack w1/Wb/Wt into MFMA-fragment-ordered bf16 + proj param table ----
// layout: [ktile][colTile(16)][lane(64)][e(8)];  k = ktile*32 + (lane>>4)*8 + e,
// col = colTile*16 + (lane&15)
__global__ __launch_bounds__(256)
void k_pack(const float* __restrict__ w1, const float* __restrict__ Wb,
            const float* __restrict__ Wt, const float* __restrict__ b1,
            const float* __restrict__ pg, const float* __restrict__ pbeta,
            const float* __restrict__ w2, u16* __restrict__ pk1,
            u16* __restrict__ pkb, u16* __restrict__ pkt,
            float4* __restrict__ pp) {
  int idx = blockIdx.x * 256 + threadIdx.x;
  if (idx < 32768) {                       // w1: K=128 padded from 107
    int e = idx & 7, lane = (idx >> 3) & 63, ct = (idx >> 9) & 15, kk = idx >> 13;
    int k = kk * 32 + (lane >> 4) * 8 + e, col = ct * 16 + (lane & 15);
    pk1[idx] = (u16)(k < kTA ? bf16rn(w1[(size_t)k * 256 + col]) : 0);
  } else if (idx < 163840) {
    int j = idx - 32768;
    const float* W = (j < 65536) ? Wb : Wt;
    u16* pk = (j < 65536) ? pkb : pkt;
    int t = j & 65535;
    int e = t & 7, lane = (t >> 3) & 63, ct = (t >> 9) & 15, kt = t >> 13;
    int k = kt * 32 + (lane >> 4) * 8 + e, col = ct * 16 + (lane & 15);
    pk[t] = (u16)bf16rn(W[(size_t)k * 256 + col]);
  } else if (idx < 163840 + 256) {
    int col = idx - 163840;
    pp[col] = make_float4(b1[col], pg[col], pbeta[col], w2[col]);
  }
}

// ---- fp32 -> bf16 convert (x -> xb), 8 elements/thread ----
__global__ __launch_bounds__(256)
void k_cvt(const float* __restrict__ in, u16* __restrict__ out) {
  size_t i = (size_t)(blockIdx.x * 256 + threadIdx.x) * 8;
  float4 a = *(const float4*)(in + i);
  float4 b = *(const float4*)(in + i + 4);
  uint4 o = make_uint4(pack2(a.x, a.y), pack2(a.z, a.w),
                       pack2(b.x, b.y), pack2(b.z, b.w));
  *(uint4*)(out + i) = o;
}

// ---- fused edge prep for both graphs: degree + count ----
__global__ __launch_bounds__(256)
void k_edge_prep_both(const int* __restrict__ bcol, const float* __restrict__ bw,
                      const int* __restrict__ tcol, const float* __restrict__ tw,
                      float* __restrict__ deg_b, int* __restrict__ cnt_b,
                      float* __restrict__ deg_t, int* __restrict__ cnt_t) {
  int e = blockIdx.x * 256 + threadIdx.x;
  if (e < kEB) {
    int c = bcol[e];
    atomicAdd(&deg_b[c], bw[e]);
    atomicAdd(&cnt_b[c], 1);
  } else {
    int t = e - kEB;
    int c = tcol[t];
    atomicAdd(&deg_t[c], tw[t]);
    atomicAdd(&cnt_t[c], 1);
  }
}

// ---- exclusive scan (one block per graph) ----
__global__ __launch_bounds__(256)
void k_scan_both(const int* __restrict__ cnt_b, int* __restrict__ base_b,
                 int* __restrict__ cur_b, const int* __restrict__ cnt_t,
                 int* __restrict__ base_t, int* __restrict__ cur_t) {
  const int* cnt = blockIdx.x ? cnt_t : cnt_b;
  int* base = blockIdx.x ? base_t : base_b;
  int* cur  = blockIdx.x ? cur_t : cur_b;
  __shared__ int part[256];
  int tid = threadIdx.x;
  int per = kN >> 8;
  int i0 = tid * per;
  int s = 0;
  for (int k = 0; k < per; ++k) s += cnt[i0 + k];
  part[tid] = s;
  __syncthreads();
  for (int off = 1; off < 256; off <<= 1) {
    int v = (tid >= off) ? part[tid - off] : 0;
    __syncthreads();
    part[tid] += v;
    __syncthreads();
  }
  int run = (tid == 0) ? 0 : part[tid - 1];
  for (int k = 0; k < per; ++k) {
    base[i0 + k] = run; cur[i0 + k] = run; run += cnt[i0 + k];
  }
  if (tid == 255) base[kN] = run;
}

__global__ __launch_bounds__(256)
void k_dis_both(const float* __restrict__ deg_b, float* __restrict__ dis_b,
                const float* __restrict__ deg_t, float* __restrict__ dis_t) {
  int i = blockIdx.x * 256 + threadIdx.x;
  if (i < kN) {
    float d = deg_b[i] + 1.0f;
    dis_b[i] = (d > 0.f) ? rsqrtf(d) : 0.f;
  } else {
    int t = i - kN;
    float d = deg_t[t] + 1.0f;
    dis_t[t] = (d > 0.f) ? rsqrtf(d) : 0.f;
  }
}

// ---- CSR fill for both graphs: per edge store (src, norm) packed ----
__global__ __launch_bounds__(256)
void k_fill_both(const int* __restrict__ bei, const float* __restrict__ bw,
                 const float* __restrict__ dis_b, int* __restrict__ cur_b,
                 int2* __restrict__ csr_b, const int* __restrict__ tei,
                 const float* __restrict__ tw, const float* __restrict__ dis_t,
                 int* __restrict__ cur_t, int2* __restrict__ csr_t) {
  int e = blockIdx.x * 256 + threadIdx.x;
  if (e < kEB) {
    int r = bei[e], c = bei[kEB + e];
    float nrm = dis_b[r] * bw[e] * dis_b[c];
    int pos = atomicAdd(&cur_b[c], 1);
    csr_b[pos] = make_int2(r, __float_as_int(nrm));
  } else {
    int t = e - kEB;
    int r = tei[t], c = tei[kET + t];
    float nrm = dis_t[r] * tw[t] * dis_t[c];
    int pos = atomicAdd(&cur_t[c], 1);
    csr_t[pos] = make_int2(r, __float_as_int(nrm));
  }
}

// ---- bf16-MFMA GEMM: Cb[M,256] = Ab[M,256] @ W, all bf16 (fp32 accum) ----
// 32 rows/block, 4 waves x 64 cols, packed W fragments, A via global_load_lds.
__global__ __launch_bounds__(256)
void k_gemm_mfma(const u16* __restrict__ Ab, const u16* __restrict__ pkW,
                 u16* __restrict__ Cb) {
  __shared__ __align__(16) u16 Atile[32 * 256];   // 16 KB, swizzled (512B rows)
  int tid = threadIdx.x;
  int w = tid >> 6, lane = tid & 63, low4 = lane & 15, hi = lane >> 4;
  int row0 = blockIdx.x * 32;

  const char* asrc = (const char*)(Ab + (size_t)row0 * 256);
#pragma unroll
  for (int i = 0; i < 4; ++i) {
    u32 d = (u32)(((i * 4 + w) * 64 + lane) * 16);
    GLOAD_LDS16(asrc + swz512(d), (char*)Atile + (i * 4 + w) * 1024);
  }

  floatx4 acc[2][4];
#pragma unroll
  for (int rt = 0; rt < 2; ++rt)
#pragma unroll
    for (int nn = 0; nn < 4; ++nn) acc[rt][nn] = (floatx4){0.f, 0.f, 0.f, 0.f};

  __syncthreads();   // drains vmcnt -> A tile ready

#pragma unroll
  for (int kt = 0; kt < 8; ++kt) {
    short8 bfr[4];
    const u16* pw = pkW + ((size_t)(kt * 16 + w * 4) * 64 + lane) * 8;
#pragma unroll
    for (int nn = 0; nn < 4; ++nn) bfr[nn] = *(const short8*)(pw + nn * 512);
    short8 afr[2];
#pragma unroll
    for (int rt = 0; rt < 2; ++rt) {
      u32 p = (u32)((rt * 16 + low4) * 512 + (kt * 32 + hi * 8) * 2);
      afr[rt] = *(const short8*)((const char*)Atile + swz512(p));
    }
#pragma unroll
    for (int rt = 0; rt < 2; ++rt)
#pragma unroll
      for (int nn = 0; nn < 4; ++nn)
        acc[rt][nn] = __builtin_amdgcn_mfma_f32_16x16x32_bf16(afr[rt], bfr[nn],
                                                              acc[rt][nn], 0, 0, 0);
  }
#pragma unroll
  for (int rt = 0; rt < 2; ++rt)
#pragma unroll
    for (int nn = 0; nn < 4; ++nn)
#pragma unroll
      for (int j = 0; j < 4; ++j) {
        int row = row0 + rt * 16 + hi * 4 + j;
        int col = w * 64 + nn * 16 + low4;
        Cb[(size_t)row * 256 + col] = (u16)bf16rn(acc[rt][nn][j]);
      }
}

// ---- temporal edge MLP via MFMA: persistent B, multi-tile blocks ----
// 512 blocks (2/CU), 8 waves each. Stage pk1 ONCE into 64 KB LDS, one
// barrier, then loop 4 independent 128-edge tiles with no further syncs
// (Btile read-only). Stage traffic 128->32 MB; tile iterations overlap.
#define PROJ_TILES 4
__global__ __launch_bounds__(512)
void k_proj_mfma(const float* __restrict__ attr, const u16* __restrict__ pk1,
                 const float* __restrict__ b1, const float4* __restrict__ pp,
                 const float* __restrict__ b2, float* __restrict__ temp_w) {
  __shared__ __align__(16) u16 Btile[32768];   // 64 KB = whole packed w1
  int tid = threadIdx.x;
  int w = tid >> 6, lane = tid & 63, low4 = lane & 15, hi = lane >> 4;

  // stage pk1: 8 iters x 512 threads x 16 B, linear (wave-uniform dest + lane*16)
#pragma unroll
  for (int it = 0; it < 8; ++it) {
    int chunk = it * 512 + tid;
    GLOAD_LDS16((const char*)pk1 + (size_t)chunk * 16,
                (char*)Btile + (it * 512 + w * 64) * 16);
  }

  // per-lane params for its 16 cols (col = nn*16 + low4): (b1, g, beta, w2)
  float4 ppv[4];   // loaded on the fly below to limit VGPR; b2 scalar now
  float b2s = b2[0];

  __syncthreads();   // drains vmcnt -> Btile ready

  for (int t = 0; t < PROJ_TILES; ++t) {
    int e0 = (blockIdx.x * PROJ_TILES + t) * 128 + w * 16;
    const float* rowp = attr + (size_t)(e0 + low4) * kTA;

    // A fragments: row = low4, k = kk*32 + hi*8 + e (zero-pad k >= 107)
    short8 a[4];
#pragma unroll
    for (int kk = 0; kk < 4; ++kk) {
      int kb = kk * 32 + hi * 8;
      float v[8];
#pragma unroll
      for (int e = 0; e < 8; ++e)
        v[e] = (kk < 3 || kb + e < kTA) ? rowp[kb + e] : 0.f;
      union { short8 s8; uint4 u4; } fr;
      fr.u4 = make_uint4(cvtpk(v[0], v[1]), cvtpk(v[2], v[3]),
                         cvtpk(v[4], v[5]), cvtpk(v[6], v[7]));
      a[kk] = fr.s8;
    }

    u32 hvpk[16][2];
    float s1[4] = {0.f, 0.f, 0.f, 0.f}, s2[4] = {0.f, 0.f, 0.f, 0.f};
#pragma unroll
    for (int nn = 0; nn < 16; ++nn) {
      floatx4 acc = (floatx4){0.f, 0.f, 0.f, 0.f};
#pragma unroll
      for (int kk = 0; kk < 4; ++kk) {
        short8 bfr = *(const short8*)(Btile + ((size_t)(kk * 16 + nn) * 64 + lane) * 8);
        acc = __builtin_amdgcn_mfma_f32_16x16x32_bf16(a[kk], bfr, acc, 0, 0, 0);
      }
      float b1v = b1[nn * 16 + low4];
      float h0 = acc[0] + b1v, h1 = acc[1] + b1v, h2 = acc[2] + b1v, h3 = acc[3] + b1v;
      s1[0] += h0; s2[0] += h0 * h0;
      s1[1] += h1; s2[1] += h1 * h1;
      s1[2] += h2; s2[2] += h2 * h2;
      s1[3] += h3; s2[3] += h3 * h3;
      hvpk[nn][0] = cvtpk(h0, h1);
      hvpk[nn][1] = cvtpk(h2, h3);
    }

    // per-row LN stats: reduce over the 16 low4 lanes
    float mean[4], inv[4];
#pragma unroll
    for (int j = 0; j < 4; ++j) {
#pragma unroll
      for (int m = 1; m < 16; m <<= 1) {
        s1[j] += __shfl_xor(s1[j], m, 64);
        s2[j] += __shfl_xor(s2[j], m, 64);
      }
      mean[j] = s1[j] * (1.f / 256);
      inv[j] = rsqrtf(s2[j] * (1.f / 256) - mean[j] * mean[j] + kEps);
    }

    // y = relu(LN(hv)); d_j = sum_cols y * w2
    float d[4] = {0.f, 0.f, 0.f, 0.f};
#pragma unroll
    for (int nn = 0; nn < 16; ++nn) {
      float4 p = pp[nn * 16 + low4];   // (b1, g, beta, w2) — L2-resident 4 KB
      float h0 = bf2f((u16)(hvpk[nn][0] & 0xFFFF));
      float h1 = bf2f((u16)(hvpk[nn][0] >> 16));
      float h2 = bf2f((u16)(hvpk[nn][1] & 0xFFFF));
      float h3 = bf2f((u16)(hvpk[nn][1] >> 16));
      d[0] += fmaxf((h0 - mean[0]) * inv[0] * p.y + p.z, 0.f) * p.w;
      d[1] += fmaxf((h1 - mean[1]) * inv[1] * p.y + p.z, 0.f) * p.w;
      d[2] += fmaxf((h2 - mean[2]) * inv[2] * p.y + p.z, 0.f) * p.w;
      d[3] += fmaxf((h3 - mean[3]) * inv[3] * p.y + p.z, 0.f) * p.w;
    }
#pragma unroll
    for (int j = 0; j < 4; ++j) {
#pragma unroll
      for (int m = 1; m < 16; m <<= 1) d[j] += __shfl_xor(d[j], m, 64);
      if (low4 == 0) temp_w[e0 + hi * 4 + j] = d[j] + b2s;
    }
  }
  (void)ppv;
}

// ---- fused gather-aggregate (bf16 h) + bias + residual + LN + relu ----
// Edge loop unrolled x2: both neighbor-row loads issued before FMAs (2x MLP).
// FINAL=0: resid fp32 (x), out bf16 (sb). FINAL=1: resid bf16 (sb), out fp32.
template <int FINAL>
__global__ __launch_bounds__(256)
void k_agg_ln(const u16* __restrict__ h, const void* __restrict__ residv,
              const float* __restrict__ x0, const int2* __restrict__ csr,
              const int* __restrict__ basep, const float* __restrict__ dis,
              const float* __restrict__ bias, const float* __restrict__ g1,
              const float* __restrict__ b1, const float* __restrict__ g2,
              const float* __restrict__ b2, void* __restrict__ outv) {
  int wave = threadIdx.x >> 6, lane = threadIdx.x & 63;
  int node = (blockIdx.x << 2) + wave;
  int c = lane << 2;
  float di = dis[node];
  ushort4 hs = *(const ushort4*)(h + (size_t)node * HN + c);
  float sl = di * di;
  float4 acc = make_float4(bf2f(hs.x) * sl, bf2f(hs.y) * sl,
                           bf2f(hs.z) * sl, bf2f(hs.w) * sl);
  int e0 = basep[node], e1 = basep[node + 1];
  int k = e0;
  for (; k + 2 <= e1; k += 2) {
    int2 pa = csr[k];
    int2 pb = csr[k + 1];
    float na = __int_as_float(pa.y), nb = __int_as_float(pb.y);
    ushort4 ha = *(const ushort4*)(h + (size_t)pa.x * HN + c);
    ushort4 hbv = *(const ushort4*)(h + (size_t)pb.x * HN + c);
    acc.x += na * bf2f(ha.x) + nb * bf2f(hbv.x);
    acc.y += na * bf2f(ha.y) + nb * bf2f(hbv.y);
    acc.z += na * bf2f(ha.z) + nb * bf2f(hbv.z);
    acc.w += na * bf2f(ha.w) + nb * bf2f(hbv.w);
  }
  if (k < e1) {
    int2 p = csr[k];
    float nrm = __int_as_float(p.y);
    ushort4 hv = *(const ushort4*)(h + (size_t)p.x * HN + c);
    acc.x += nrm * bf2f(hv.x); acc.y += nrm * bf2f(hv.y);
    acc.z += nrm * bf2f(hv.z); acc.w += nrm * bf2f(hv.w);
  }
  float4 bb = *(const float4*)(bias + c);
  float4 rr;
  if (!FINAL) {
    rr = *(const float4*)((const float*)residv + (size_t)node * HN + c);
  } else {
    ushort4 rv = *(const ushort4*)((const u16*)residv + (size_t)node * HN + c);
    rr = make_float4(bf2f(rv.x), bf2f(rv.y), bf2f(rv.z), bf2f(rv.w));
  }
  float v0 = acc.x + bb.x + rr.x;
  float v1 = acc.y + bb.y + rr.y;
  float v2 = acc.z + bb.z + rr.z;
  float v3 = acc.w + bb.w + rr.w;
  float sum = wsum(v0 + v1 + v2 + v3);
  float ss  = wsum(v0 * v0 + v1 * v1 + v2 * v2 + v3 * v3);
  float mean = sum * (1.f / HN);
  float inv = rsqrtf(ss * (1.f / HN) - mean * mean + kEps);
  float4 g = *(const float4*)(g1 + c);
  float4 b = *(const float4*)(b1 + c);
  float y0 = fmaxf((v0 - mean) * inv * g.x + b.x, 0.f);
  float y1 = fmaxf((v1 - mean) * inv * g.y + b.y, 0.f);
  float y2 = fmaxf((v2 - mean) * inv * g.z + b.z, 0.f);
  float y3 = fmaxf((v3 - mean) * inv * g.w + b.w, 0.f);
  if (!FINAL) {
    uint2 o = make_uint2(pack2(y0, y1), pack2(y2, y3));
    *(uint2*)((u16*)outv + (size_t)node * HN + c) = o;
  } else {
    float4 xx = *(const float4*)(x0 + (size_t)node * HN + c);
    float z0 = y0 + xx.x, z1 = y1 + xx.y, z2 = y2 + xx.z, z3 = y3 + xx.w;
    float s2 = wsum(z0 + z1 + z2 + z3);
    float q2 = wsum(z0 * z0 + z1 * z1 + z2 * z2 + z3 * z3);
    float m2 = s2 * (1.f / HN);
    float i2 = rsqrtf(q2 * (1.f / HN) - m2 * m2 + kEps);
    float4 G = *(const float4*)(g2 + c);
    float4 B = *(const float4*)(b2 + c);
    float4 o = make_float4((z0 - m2) * i2 * G.x + B.x, (z1 - m2) * i2 * G.y + B.y,
                           (z2 - m2) * i2 * G.z + B.z, (z3 - m2) * i2 * G.w + B.w);
    *(float4*)((float*)outv + (size_t)node * HN + c) = o;
  }
}

extern "C" void kernel_launch(void* const* d_in, const int* in_sizes, int n_in,
                              void* d_out, int out_size, void* d_ws, size_t ws_size,
                              hipStream_t stream) {
  const float* x     = (const float*)d_in[0];
  const int*   bei   = (const int*)d_in[1];
  const float* bew   = (const float*)d_in[2];
  const int*   tei   = (const int*)d_in[3];
  const float* tattr = (const float*)d_in[4];
  const float* Wb    = (const float*)d_in[5];
  const float* bb    = (const float*)d_in[6];
  const float* Wt    = (const float*)d_in[7];
  const float* bt    = (const float*)d_in[8];
  const float* gs    = (const float*)d_in[9];
  const float* bs    = (const float*)d_in[10];
  const float* gt    = (const float*)d_in[11];
  const float* btn   = (const float*)d_in[12];
  const float* pw1   = (const float*)d_in[13];
  const float* pb1   = (const float*)d_in[14];
  const float* pg    = (const float*)d_in[15];
  const float* pbeta = (const float*)d_in[16];
  const float* pw2   = (const float*)d_in[17];
  const float* pb2   = (const float*)d_in[18];
  float* outp = (float*)d_out;

  size_t off = 0;
  auto alloc = [&](size_t bytes) -> void* {
    void* p = (char*)d_ws + off;
    off += (bytes + 255) & ~(size_t)255;
    return p;
  };
  float* deg_b = (float*)alloc(kN * 4);
  float* deg_t = (float*)alloc(kN * 4);
  int*   cnt_b = (int*)alloc(kN * 4);
  int*   cnt_t = (int*)alloc(kN * 4);       // deg_b..cnt_t contiguous: one memset
  float* dis_b = (float*)alloc(kN * 4);
  float* dis_t = (float*)alloc(kN * 4);
  int*   base_b = (int*)alloc((kN + 1) * 4);
  int*   base_t = (int*)alloc((kN + 1) * 4);
  int*   cur_b  = (int*)alloc(kN * 4);
  int*   cur_t  = (int*)alloc(kN * 4);
  float* tmpw   = (float*)alloc(kET * 4);
  int2*  csr_b  = (int2*)alloc((size_t)kEB * 8);
  int2*  csr_t  = (int2*)alloc((size_t)kET * 8);
  u16*   pk1 = (u16*)alloc(32768 * 2);
  u16*   pkb = (u16*)alloc(65536 * 2);
  u16*   pkt = (u16*)alloc(65536 * 2);
  float4* pp = (float4*)alloc(256 * 16);
  u16*   xb  = (u16*)alloc((size_t)kN * HN * 2);
  u16*   hb  = (u16*)alloc((size_t)kN * HN * 2);
  u16*   sb  = (u16*)alloc((size_t)kN * HN * 2);
  (void)ws_size; (void)in_sizes; (void)n_in; (void)out_size;

  hipMemsetAsync(deg_b, 0, (size_t)4 * kN * 4, stream);

  // const prep
  k_pack<<<641, 256, 0, stream>>>(pw1, Wb, Wt, pb1, pg, pbeta, pw2,
                                  pk1, pkb, pkt, pp);
  k_cvt<<<kN * HN / 8 / 256, 256, 0, stream>>>(x, xb);

  // temporal edge weights (independent of node pipeline)
  k_proj_mfma<<<kET / 128 / PROJ_TILES, 512, 0, stream>>>(tattr, pk1, pb1, pp,
                                                          pb2, tmpw);

  // graph structure for both graphs
  k_edge_prep_both<<<(kEB + kET) / 256, 256, 0, stream>>>(
      bei + kEB, bew, tei + kET, tmpw, deg_b, cnt_b, deg_t, cnt_t);
  k_scan_both<<<2, 256, 0, stream>>>(cnt_b, base_b, cur_b, cnt_t, base_t, cur_t);
  k_dis_both<<<2 * kN / 256, 256, 0, stream>>>(deg_b, dis_b, deg_t, dis_t);
  k_fill_both<<<(kEB + kET) / 256, 256, 0, stream>>>(
      bei, bew, dis_b, cur_b, csr_b, tei, tmpw, dis_t, cur_t, csr_t);

  // stage 1: bold GCN
  k_gemm_mfma<<<kN / 32, 256, 0, stream>>>(xb, pkb, hb);
  k_agg_ln<0><<<kN / 4, 256, 0, stream>>>(hb, x, nullptr, csr_b, base_b, dis_b,
                                          bb, gs, bs, nullptr, nullptr, sb);
  // stage 2: temporal GCN + final LN
  k_gemm_mfma<<<kN / 32, 256, 0, stream>>>(sb, pkt, hb);
  k_agg_ln<1><<<kN / 4, 256, 0, stream>>>(hb, sb, x, csr_t, base_t, dis_t,
                                          bt, gt, btn, gs, bs, outp);
}

// Round 10
// 274.698 us; speedup vs baseline: 1.2303x; 1.0121x over previous
//
#include <hip/hip_runtime.h>

constexpr int kN  = 16384;
constexpr int kEB = 524288;
constexpr int kET = 262144;
constexpr int kTA = 107;
constexpr float kEps = 1e-5f;
#define HN 256

typedef __attribute__((ext_vector_type(8))) short short8;
typedef __attribute__((ext_vector_type(4))) float floatx4;
typedef unsigned short u16;
typedef unsigned int u32;

#define GLOAD_LDS16(gp, lp)                                                    \
  __builtin_amdgcn_global_load_lds(                                            \
      (const __attribute__((address_space(1))) u32*)(gp),                      \
      (__attribute__((address_space(3))) u32*)(lp), 16, 0, 0)

__device__ __forceinline__ float wsum(float v) {
#pragma unroll
  for (int m = 1; m < 64; m <<= 1) v += __shfl_xor(v, m, 64);
  return v;
}

__device__ __forceinline__ u32 bf16rn(float f) {
  u32 u = __float_as_uint(f);
  return (u + 0x7FFFu + ((u >> 16) & 1u)) >> 16;
}
__device__ __forceinline__ u32 pack2(float a, float b) {
  return bf16rn(a) | (bf16rn(b) << 16);
}
__device__ __forceinline__ float bf2f(u16 v) {
  return __uint_as_float(((u32)v) << 16);
}
__device__ __forceinline__ u32 cvtpk(float lo, float hi) {
  u32 r;
  asm("v_cvt_pk_bf16_f32 %0, %1, %2" : "=v"(r) : "v"(lo), "v"(hi));
  return r;
}
// XOR swizzle for 512B-row tiles (bits 9-11 -> 4-6)
__device__ __forceinline__ u32 swz512(u32 b) { return b ^ (((b >> 9) & 7u) << 4); }

// ---- pack w1/Wb/Wt into MFMA-fragment-ordered bf16 + proj param table ----
// layout: [ktile][colTile(16)][lane(64)][e(8)];  k = ktile*32 + (lane>>4)*8 + e,
// col = colTile*16 + (lane&15)
__global__ __launch_bounds__(256)
void k_pack(const float* __restrict__ w1, const float* __restrict__ Wb,
            const float* __restrict__ Wt, const float* __restrict__ b1,
            const float* __restrict__ pg, const float* __restrict__ pbeta,
            const float* __restrict__ w2, u16* __restrict__ pk1,
            u16* __restrict__ pkb, u16* __restrict__ pkt,
            float4* __restrict__ pp) {
  int idx = blockIdx.x * 256 + threadIdx.x;
  if (idx < 32768) {                       // w1: K=128 padded from 107
    int e = idx & 7, lane = (idx >> 3) & 63, ct = (idx >> 9) & 15, kk = idx >> 13;
    int k = kk * 32 + (lane >> 4) * 8 + e, col = ct * 16 + (lane & 15);
    pk1[idx] = (u16)(k < kTA ? bf16rn(w1[(size_t)k * 256 + col]) : 0);
  } else if (idx < 163840) {
    int j = idx - 32768;
    const float* W = (j < 65536) ? Wb : Wt;
    u16* pk = (j < 65536) ? pkb : pkt;
    int t = j & 65535;
    int e = t & 7, lane = (t >> 3) & 63, ct = (t >> 9) & 15, kt = t >> 13;
    int k = kt * 32 + (lane >> 4) * 8 + e, col = ct * 16 + (lane & 15);
    pk[t] = (u16)bf16rn(W[(size_t)k * 256 + col]);
  } else if (idx < 163840 + 256) {
    int col = idx - 163840;
    pp[col] = make_float4(b1[col], pg[col], pbeta[col], w2[col]);
  }
}

// ---- fp32 -> bf16 convert (x -> xb), 8 elements/thread ----
__global__ __launch_bounds__(256)
void k_cvt(const float* __restrict__ in, u16* __restrict__ out) {
  size_t i = (size_t)(blockIdx.x * 256 + threadIdx.x) * 8;
  float4 a = *(const float4*)(in + i);
  float4 b = *(const float4*)(in + i + 4);
  uint4 o = make_uint4(pack2(a.x, a.y), pack2(a.z, a.w),
                       pack2(b.x, b.y), pack2(b.z, b.w));
  *(uint4*)(out + i) = o;
}

// ---- fused edge prep for both graphs: degree + count ----
__global__ __launch_bounds__(256)
void k_edge_prep_both(const int* __restrict__ bcol, const float* __restrict__ bw,
                      const int* __restrict__ tcol, const float* __restrict__ tw,
                      float* __restrict__ deg_b, int* __restrict__ cnt_b,
                      float* __restrict__ deg_t, int* __restrict__ cnt_t) {
  int e = blockIdx.x * 256 + threadIdx.x;
  if (e < kEB) {
    int c = bcol[e];
    atomicAdd(&deg_b[c], bw[e]);
    atomicAdd(&cnt_b[c], 1);
  } else {
    int t = e - kEB;
    int c = tcol[t];
    atomicAdd(&deg_t[c], tw[t]);
    atomicAdd(&cnt_t[c], 1);
  }
}

// ---- exclusive scan (one block per graph) ----
__global__ __launch_bounds__(256)
void k_scan_both(const int* __restrict__ cnt_b, int* __restrict__ base_b,
                 int* __restrict__ cur_b, const int* __restrict__ cnt_t,
                 int* __restrict__ base_t, int* __restrict__ cur_t) {
  const int* cnt = blockIdx.x ? cnt_t : cnt_b;
  int* base = blockIdx.x ? base_t : base_b;
  int* cur  = blockIdx.x ? cur_t : cur_b;
  __shared__ int part[256];
  int tid = threadIdx.x;
  int per = kN >> 8;
  int i0 = tid * per;
  int s = 0;
  for (int k = 0; k < per; ++k) s += cnt[i0 + k];
  part[tid] = s;
  __syncthreads();
  for (int off = 1; off < 256; off <<= 1) {
    int v = (tid >= off) ? part[tid - off] : 0;
    __syncthreads();
    part[tid] += v;
    __syncthreads();
  }
  int run = (tid == 0) ? 0 : part[tid - 1];
  for (int k = 0; k < per; ++k) {
    base[i0 + k] = run; cur[i0 + k] = run; run += cnt[i0 + k];
  }
  if (tid == 255) base[kN] = run;
}

__global__ __launch_bounds__(256)
void k_dis_both(const float* __restrict__ deg_b, float* __restrict__ dis_b,
                const float* __restrict__ deg_t, float* __restrict__ dis_t) {
  int i = blockIdx.x * 256 + threadIdx.x;
  if (i < kN) {
    float d = deg_b[i] + 1.0f;
    dis_b[i] = (d > 0.f) ? rsqrtf(d) : 0.f;
  } else {
    int t = i - kN;
    float d = deg_t[t] + 1.0f;
    dis_t[t] = (d > 0.f) ? rsqrtf(d) : 0.f;
  }
}

// ---- CSR fill for both graphs: per edge store (src, norm) packed ----
__global__ __launch_bounds__(256)
void k_fill_both(const int* __restrict__ bei, const float* __restrict__ bw,
                 const float* __restrict__ dis_b, int* __restrict__ cur_b,
                 int2* __restrict__ csr_b, const int* __restrict__ tei,
                 const float* __restrict__ tw, const float* __restrict__ dis_t,
                 int* __restrict__ cur_t, int2* __restrict__ csr_t) {
  int e = blockIdx.x * 256 + threadIdx.x;
  if (e < kEB) {
    int r = bei[e], c = bei[kEB + e];
    float nrm = dis_b[r] * bw[e] * dis_b[c];
    int pos = atomicAdd(&cur_b[c], 1);
    csr_b[pos] = make_int2(r, __float_as_int(nrm));
  } else {
    int t = e - kEB;
    int r = tei[t], c = tei[kET + t];
    float nrm = dis_t[r] * tw[t] * dis_t[c];
    int pos = atomicAdd(&cur_t[c], 1);
    csr_t[pos] = make_int2(r, __float_as_int(nrm));
  }
}

// ---- bf16-MFMA GEMM: Cb[M,256] = Ab[M,256] @ W, all bf16 (fp32 accum) ----
// 32 rows/block, 4 waves x 64 cols, packed W fragments, A via global_load_lds.
__global__ __launch_bounds__(256)
void k_gemm_mfma(const u16* __restrict__ Ab, const u16* __restrict__ pkW,
                 u16* __restrict__ Cb) {
  __shared__ __align__(16) u16 Atile[32 * 256];   // 16 KB, swizzled (512B rows)
  int tid = threadIdx.x;
  int w = tid >> 6, lane = tid & 63, low4 = lane & 15, hi = lane >> 4;
  int row0 = blockIdx.x * 32;

  const char* asrc = (const char*)(Ab + (size_t)row0 * 256);
#pragma unroll
  for (int i = 0; i < 4; ++i) {
    u32 d = (u32)(((i * 4 + w) * 64 + lane) * 16);
    GLOAD_LDS16(asrc + swz512(d), (char*)Atile + (i * 4 + w) * 1024);
  }

  floatx4 acc[2][4];
#pragma unroll
  for (int rt = 0; rt < 2; ++rt)
#pragma unroll
    for (int nn = 0; nn < 4; ++nn) acc[rt][nn] = (floatx4){0.f, 0.f, 0.f, 0.f};

  __syncthreads();   // drains vmcnt -> A tile ready

#pragma unroll
  for (int kt = 0; kt < 8; ++kt) {
    short8 bfr[4];
    const u16* pw = pkW + ((size_t)(kt * 16 + w * 4) * 64 + lane) * 8;
#pragma unroll
    for (int nn = 0; nn < 4; ++nn) bfr[nn] = *(const short8*)(pw + nn * 512);
    short8 afr[2];
#pragma unroll
    for (int rt = 0; rt < 2; ++rt) {
      u32 p = (u32)((rt * 16 + low4) * 512 + (kt * 32 + hi * 8) * 2);
      afr[rt] = *(const short8*)((const char*)Atile + swz512(p));
    }
#pragma unroll
    for (int rt = 0; rt < 2; ++rt)
#pragma unroll
      for (int nn = 0; nn < 4; ++nn)
        acc[rt][nn] = __builtin_amdgcn_mfma_f32_16x16x32_bf16(afr[rt], bfr[nn],
                                                              acc[rt][nn], 0, 0, 0);
  }
#pragma unroll
  for (int rt = 0; rt < 2; ++rt)
#pragma unroll
    for (int nn = 0; nn < 4; ++nn)
#pragma unroll
      for (int j = 0; j < 4; ++j) {
        int row = row0 + rt * 16 + hi * 4 + j;
        int col = w * 64 + nn * 16 + low4;
        Cb[(size_t)row * 256 + col] = (u16)bf16rn(acc[rt][nn][j]);
      }
}

// ---- temporal edge MLP via MFMA: persistent B, 16-wave blocks ----
// 512 blocks (2/CU), 1024 threads = 16 waves -> 32 waves/CU (8/SIMD) with the
// same single 64 KB Btile: doubles latency hiding vs the 8-wave version at
// identical per-wave code (VGPR 64 = the 32-waves/CU boundary). Stage once,
// one barrier, then 2 independent 256-edge passes, no further syncs.
#define PROJ_PASSES 2
__global__ __launch_bounds__(1024)
void k_proj_mfma(const float* __restrict__ attr, const u16* __restrict__ pk1,
                 const float* __restrict__ b1, const float4* __restrict__ pp,
                 const float* __restrict__ b2, float* __restrict__ temp_w) {
  __shared__ __align__(16) u16 Btile[32768];   // 64 KB = whole packed w1
  int tid = threadIdx.x;
  int w = tid >> 6, lane = tid & 63, low4 = lane & 15, hi = lane >> 4;

  // stage pk1: 4 iters x 1024 threads x 16 B, linear
#pragma unroll
  for (int it = 0; it < 4; ++it) {
    int chunk = it * 1024 + tid;
    GLOAD_LDS16((const char*)pk1 + (size_t)chunk * 16,
                (char*)Btile + (it * 1024 + w * 64) * 16);
  }

  float b2s = b2[0];

  __syncthreads();   // drains vmcnt -> Btile ready

  for (int t = 0; t < PROJ_PASSES; ++t) {
    int e0 = (blockIdx.x * PROJ_PASSES + t) * 256 + w * 16;
    const float* rowp = attr + (size_t)(e0 + low4) * kTA;

    // A fragments: row = low4, k = kk*32 + hi*8 + e (zero-pad k >= 107)
    short8 a[4];
#pragma unroll
    for (int kk = 0; kk < 4; ++kk) {
      int kb = kk * 32 + hi * 8;
      float v[8];
#pragma unroll
      for (int e = 0; e < 8; ++e)
        v[e] = (kk < 3 || kb + e < kTA) ? rowp[kb + e] : 0.f;
      union { short8 s8; uint4 u4; } fr;
      fr.u4 = make_uint4(cvtpk(v[0], v[1]), cvtpk(v[2], v[3]),
                         cvtpk(v[4], v[5]), cvtpk(v[6], v[7]));
      a[kk] = fr.s8;
    }

    u32 hvpk[16][2];
    float s1[4] = {0.f, 0.f, 0.f, 0.f}, s2[4] = {0.f, 0.f, 0.f, 0.f};
#pragma unroll
    for (int nn = 0; nn < 16; ++nn) {
      floatx4 acc = (floatx4){0.f, 0.f, 0.f, 0.f};
#pragma unroll
      for (int kk = 0; kk < 4; ++kk) {
        short8 bfr = *(const short8*)(Btile + ((size_t)(kk * 16 + nn) * 64 + lane) * 8);
        acc = __builtin_amdgcn_mfma_f32_16x16x32_bf16(a[kk], bfr, acc, 0, 0, 0);
      }
      float b1v = b1[nn * 16 + low4];
      float h0 = acc[0] + b1v, h1 = acc[1] + b1v, h2 = acc[2] + b1v, h3 = acc[3] + b1v;
      s1[0] += h0; s2[0] += h0 * h0;
      s1[1] += h1; s2[1] += h1 * h1;
      s1[2] += h2; s2[2] += h2 * h2;
      s1[3] += h3; s2[3] += h3 * h3;
      hvpk[nn][0] = cvtpk(h0, h1);
      hvpk[nn][1] = cvtpk(h2, h3);
    }

    // per-row LN stats: reduce over the 16 low4 lanes
    float mean[4], inv[4];
#pragma unroll
    for (int j = 0; j < 4; ++j) {
#pragma unroll
      for (int m = 1; m < 16; m <<= 1) {
        s1[j] += __shfl_xor(s1[j], m, 64);
        s2[j] += __shfl_xor(s2[j], m, 64);
      }
      mean[j] = s1[j] * (1.f / 256);
      inv[j] = rsqrtf(s2[j] * (1.f / 256) - mean[j] * mean[j] + kEps);
    }

    // y = relu(LN(hv)); d_j = sum_cols y * w2
    float d[4] = {0.f, 0.f, 0.f, 0.f};
#pragma unroll
    for (int nn = 0; nn < 16; ++nn) {
      float4 p = pp[nn * 16 + low4];   // (b1, g, beta, w2) — L2-resident 4 KB
      float h0 = bf2f((u16)(hvpk[nn][0] & 0xFFFF));
      float h1 = bf2f((u16)(hvpk[nn][0] >> 16));
      float h2 = bf2f((u16)(hvpk[nn][1] & 0xFFFF));
      float h3 = bf2f((u16)(hvpk[nn][1] >> 16));
      d[0] += fmaxf((h0 - mean[0]) * inv[0] * p.y + p.z, 0.f) * p.w;
      d[1] += fmaxf((h1 - mean[1]) * inv[1] * p.y + p.z, 0.f) * p.w;
      d[2] += fmaxf((h2 - mean[2]) * inv[2] * p.y + p.z, 0.f) * p.w;
      d[3] += fmaxf((h3 - mean[3]) * inv[3] * p.y + p.z, 0.f) * p.w;
    }
#pragma unroll
    for (int j = 0; j < 4; ++j) {
#pragma unroll
      for (int m = 1; m < 16; m <<= 1) d[j] += __shfl_xor(d[j], m, 64);
      if (low4 == 0) temp_w[e0 + hi * 4 + j] = d[j] + b2s;
    }
  }
}

// ---- fused gather-aggregate (bf16 h) + bias + residual + LN + relu ----
// Edge loop unrolled x4: 4 independent row loads in flight (gather MLP=4).
// FINAL=0: resid fp32 (x), out bf16 (sb). FINAL=1: resid bf16 (sb), out fp32.
template <int FINAL>
__global__ __launch_bounds__(256)
void k_agg_ln(const u16* __restrict__ h, const void* __restrict__ residv,
              const float* __restrict__ x0, const int2* __restrict__ csr,
              const int* __restrict__ basep, const float* __restrict__ dis,
              const float* __restrict__ bias, const float* __restrict__ g1,
              const float* __restrict__ b1, const float* __restrict__ g2,
              const float* __restrict__ b2, void* __restrict__ outv) {
  int wave = threadIdx.x >> 6, lane = threadIdx.x & 63;
  int node = (blockIdx.x << 2) + wave;
  int c = lane << 2;
  float di = dis[node];
  ushort4 hs = *(const ushort4*)(h + (size_t)node * HN + c);
  float sl = di * di;
  float4 acc = make_float4(bf2f(hs.x) * sl, bf2f(hs.y) * sl,
                           bf2f(hs.z) * sl, bf2f(hs.w) * sl);
  int e0 = basep[node], e1 = basep[node + 1];
  int k = e0;
  for (; k + 4 <= e1; k += 4) {
    int2 p0 = csr[k], p1v = csr[k + 1], p2v = csr[k + 2], p3 = csr[k + 3];
    float n0 = __int_as_float(p0.y), n1 = __int_as_float(p1v.y);
    float n2 = __int_as_float(p2v.y), n3 = __int_as_float(p3.y);
    ushort4 h0 = *(const ushort4*)(h + (size_t)p0.x * HN + c);
    ushort4 h1 = *(const ushort4*)(h + (size_t)p1v.x * HN + c);
    ushort4 h2 = *(const ushort4*)(h + (size_t)p2v.x * HN + c);
    ushort4 h3 = *(const ushort4*)(h + (size_t)p3.x * HN + c);
    acc.x += n0 * bf2f(h0.x) + n1 * bf2f(h1.x) + n2 * bf2f(h2.x) + n3 * bf2f(h3.x);
    acc.y += n0 * bf2f(h0.y) + n1 * bf2f(h1.y) + n2 * bf2f(h2.y) + n3 * bf2f(h3.y);
    acc.z += n0 * bf2f(h0.z) + n1 * bf2f(h1.z) + n2 * bf2f(h2.z) + n3 * bf2f(h3.z);
    acc.w += n0 * bf2f(h0.w) + n1 * bf2f(h1.w) + n2 * bf2f(h2.w) + n3 * bf2f(h3.w);
  }
  for (; k < e1; ++k) {
    int2 p = csr[k];
    float nrm = __int_as_float(p.y);
    ushort4 hv = *(const ushort4*)(h + (size_t)p.x * HN + c);
    acc.x += nrm * bf2f(hv.x); acc.y += nrm * bf2f(hv.y);
    acc.z += nrm * bf2f(hv.z); acc.w += nrm * bf2f(hv.w);
  }
  float4 bb = *(const float4*)(bias + c);
  float4 rr;
  if (!FINAL) {
    rr = *(const float4*)((const float*)residv + (size_t)node * HN + c);
  } else {
    ushort4 rv = *(const ushort4*)((const u16*)residv + (size_t)node * HN + c);
    rr = make_float4(bf2f(rv.x), bf2f(rv.y), bf2f(rv.z), bf2f(rv.w));
  }
  float v0 = acc.x + bb.x + rr.x;
  float v1 = acc.y + bb.y + rr.y;
  float v2 = acc.z + bb.z + rr.z;
  float v3 = acc.w + bb.w + rr.w;
  float sum = wsum(v0 + v1 + v2 + v3);
  float ss  = wsum(v0 * v0 + v1 * v1 + v2 * v2 + v3 * v3);
  float mean = sum * (1.f / HN);
  float inv = rsqrtf(ss * (1.f / HN) - mean * mean + kEps);
  float4 g = *(const float4*)(g1 + c);
  float4 b = *(const float4*)(b1 + c);
  float y0 = fmaxf((v0 - mean) * inv * g.x + b.x, 0.f);
  float y1 = fmaxf((v1 - mean) * inv * g.y + b.y, 0.f);
  float y2 = fmaxf((v2 - mean) * inv * g.z + b.z, 0.f);
  float y3 = fmaxf((v3 - mean) * inv * g.w + b.w, 0.f);
  if (!FINAL) {
    uint2 o = make_uint2(pack2(y0, y1), pack2(y2, y3));
    *(uint2*)((u16*)outv + (size_t)node * HN + c) = o;
  } else {
    float4 xx = *(const float4*)(x0 + (size_t)node * HN + c);
    float z0 = y0 + xx.x, z1 = y1 + xx.y, z2 = y2 + xx.z, z3 = y3 + xx.w;
    float s2 = wsum(z0 + z1 + z2 + z3);
    float q2 = wsum(z0 * z0 + z1 * z1 + z2 * z2 + z3 * z3);
    float m2 = s2 * (1.f / HN);
    float i2 = rsqrtf(q2 * (1.f / HN) - m2 * m2 + kEps);
    float4 G = *(const float4*)(g2 + c);
    float4 B = *(const float4*)(b2 + c);
    float4 o = make_float4((z0 - m2) * i2 * G.x + B.x, (z1 - m2) * i2 * G.y + B.y,
                           (z2 - m2) * i2 * G.z + B.z, (z3 - m2) * i2 * G.w + B.w);
    *(float4*)((float*)outv + (size_t)node * HN + c) = o;
  }
}

extern "C" void kernel_launch(void* const* d_in, const int* in_sizes, int n_in,
                              void* d_out, int out_size, void* d_ws, size_t ws_size,
                              hipStream_t stream) {
  const float* x     = (const float*)d_in[0];
  const int*   bei   = (const int*)d_in[1];
  const float* bew   = (const float*)d_in[2];
  const int*   tei   = (const int*)d_in[3];
  const float* tattr = (const float*)d_in[4];
  const float* Wb    = (const float*)d_in[5];
  const float* bb    = (const float*)d_in[6];
  const float* Wt    = (const float*)d_in[7];
  const float* bt    = (const float*)d_in[8];
  const float* gs    = (const float*)d_in[9];
  const float* bs    = (const float*)d_in[10];
  const float* gt    = (const float*)d_in[11];
  const float* btn   = (const float*)d_in[12];
  const float* pw1   = (const float*)d_in[13];
  const float* pb1   = (const float*)d_in[14];
  const float* pg    = (const float*)d_in[15];
  const float* pbeta = (const float*)d_in[16];
  const float* pw2   = (const float*)d_in[17];
  const float* pb2   = (const float*)d_in[18];
  float* outp = (float*)d_out;

  size_t off = 0;
  auto alloc = [&](size_t bytes) -> void* {
    void* p = (char*)d_ws + off;
    off += (bytes + 255) & ~(size_t)255;
    return p;
  };
  float* deg_b = (float*)alloc(kN * 4);
  float* deg_t = (float*)alloc(kN * 4);
  int*   cnt_b = (int*)alloc(kN * 4);
  int*   cnt_t = (int*)alloc(kN * 4);       // deg_b..cnt_t contiguous: one memset
  float* dis_b = (float*)alloc(kN * 4);
  float* dis_t = (float*)alloc(kN * 4);
  int*   base_b = (int*)alloc((kN + 1) * 4);
  int*   base_t = (int*)alloc((kN + 1) * 4);
  int*   cur_b  = (int*)alloc(kN * 4);
  int*   cur_t  = (int*)alloc(kN * 4);
  float* tmpw   = (float*)alloc(kET * 4);
  int2*  csr_b  = (int2*)alloc((size_t)kEB * 8);
  int2*  csr_t  = (int2*)alloc((size_t)kET * 8);
  u16*   pk1 = (u16*)alloc(32768 * 2);
  u16*   pkb = (u16*)alloc(65536 * 2);
  u16*   pkt = (u16*)alloc(65536 * 2);
  float4* pp = (float4*)alloc(256 * 16);
  u16*   xb  = (u16*)alloc((size_t)kN * HN * 2);
  u16*   hb  = (u16*)alloc((size_t)kN * HN * 2);
  u16*   sb  = (u16*)alloc((size_t)kN * HN * 2);
  (void)ws_size; (void)in_sizes; (void)n_in; (void)out_size;

  hipMemsetAsync(deg_b, 0, (size_t)4 * kN * 4, stream);

  // const prep
  k_pack<<<641, 256, 0, stream>>>(pw1, Wb, Wt, pb1, pg, pbeta, pw2,
                                  pk1, pkb, pkt, pp);
  k_cvt<<<kN * HN / 8 / 256, 256, 0, stream>>>(x, xb);

  // temporal edge weights (independent of node pipeline)
  k_proj_mfma<<<kET / 256 / PROJ_PASSES, 1024, 0, stream>>>(tattr, pk1, pb1, pp,
                                                            pb2, tmpw);

  // graph structure for both graphs
  k_edge_prep_both<<<(kEB + kET) / 256, 256, 0, stream>>>(
      bei + kEB, bew, tei + kET, tmpw, deg_b, cnt_b, deg_t, cnt_t);
  k_scan_both<<<2, 256, 0, stream>>>(cnt_b, base_b, cur_b, cnt_t, base_t, cur_t);
  k_dis_both<<<2 * kN / 256, 256, 0, stream>>>(deg_b, dis_b, deg_t, dis_t);
  k_fill_both<<<(kEB + kET) / 256, 256, 0, stream>>>(
      bei, bew, dis_b, cur_b, csr_b, tei, tmpw, dis_t, cur_t, csr_t);

  // stage 1: bold GCN
  k_gemm_mfma<<<kN / 32, 256, 0, stream>>>(xb, pkb, hb);
  k_agg_ln<0><<<kN / 4, 256, 0, stream>>>(hb, x, nullptr, csr_b, base_b, dis_b,
                                          bb, gs, bs, nullptr, nullptr, sb);
  // stage 2: temporal GCN + final LN
  k_gemm_mfma<<<kN / 32, 256, 0, stream>>>(sb, pkt, hb);
  k_agg_ln<1><<<kN / 4, 256, 0, stream>>>(hb, sb, x, csr_t, base_t, dis_t,
                                          bt, gt, btn, gs, bs, outp);
}